// Round 1
// baseline (1277.908 us; speedup 1.0000x reference)
//
#include <hip/hip_runtime.h>
#include <math.h>

#define N_NODES 50000
#define N_EDGES 800000

__device__ __forceinline__ float gelu_f(float x){
  return 0.5f*x*(1.0f + tanhf(0.7978845608028654f*(x + 0.044715f*x*x*x)));
}

__device__ __forceinline__ void fma4x4(float4 a0,float4 a1,float4 a2,float4 a3,
                                       float4 b0,float4 b1,float4 b2,float4 b3,
                                       float acc[4][4]){
  float4 ar[4] = {a0,a1,a2,a3};
  #pragma unroll
  for (int i = 0; i < 4; ++i){
    float ax = ar[i].x, ay = ar[i].y, az = ar[i].z, aw = ar[i].w;
    acc[i][0] += ax*b0.x + ay*b1.x + az*b2.x + aw*b3.x;
    acc[i][1] += ax*b0.y + ay*b1.y + az*b2.y + aw*b3.y;
    acc[i][2] += ax*b0.z + ay*b1.z + az*b2.z + aw*b3.z;
    acc[i][3] += ax*b0.w + ay*b1.w + az*b2.w + aw*b3.w;
  }
}

// ---------------- CSR build ----------------
__global__ __launch_bounds__(256) void k_deg(const int* __restrict__ dst, int* __restrict__ deg){
  int i = blockIdx.x*256 + threadIdx.x;
  if (i < N_EDGES) atomicAdd(&deg[dst[i]], 1);
}

__global__ __launch_bounds__(1024) void k_scan(const int* __restrict__ deg,
                                               int* __restrict__ off, int* __restrict__ cursor){
  __shared__ int wsum[16];
  __shared__ int chunk_total;
  __shared__ int carry;
  int tid = threadIdx.x, lane = tid & 63, wid = tid >> 6;
  if (tid == 0) carry = 0;
  __syncthreads();
  for (int base = 0; base < N_NODES; base += 1024){
    int i = base + tid;
    int val = (i < N_NODES) ? deg[i] : 0;
    int incl = val;
    #pragma unroll
    for (int s = 1; s < 64; s <<= 1){
      int t = __shfl_up(incl, s, 64);
      if (lane >= s) incl += t;
    }
    if (lane == 63) wsum[wid] = incl;
    __syncthreads();
    if (tid < 16){
      int t = wsum[tid];
      int inc = t;
      #pragma unroll
      for (int s = 1; s < 16; s <<= 1){
        int u = __shfl_up(inc, s, 64);
        if (tid >= s) inc += u;
      }
      wsum[tid] = inc - t;           // exclusive wave offsets
      if (tid == 15) chunk_total = inc;
    }
    __syncthreads();
    int excl = carry + wsum[wid] + (incl - val);
    if (i < N_NODES){ off[i] = excl; cursor[i] = excl; }
    __syncthreads();
    if (tid == 0) carry += chunk_total;
    __syncthreads();
  }
  if (threadIdx.x == 0) off[N_NODES] = carry;
}

__global__ __launch_bounds__(256) void k_scatter(const int* __restrict__ dst,
                                                 int* __restrict__ cursor, int* __restrict__ bucket){
  int i = blockIdx.x*256 + threadIdx.x;
  if (i < N_EDGES){
    int d = dst[i];
    int pos = atomicAdd(&cursor[d], 1);
    bucket[pos] = i;
  }
}

// ---------------- node projections: LN(x) -> q,k,v,x_r ----------------
__global__ __launch_bounds__(256) void k_nodeproj(
  const float* __restrict__ x, const float* __restrict__ lnw, const float* __restrict__ lnb,
  const float* __restrict__ Wq, const float* __restrict__ bq,
  const float* __restrict__ Wk, const float* __restrict__ bk,
  const float* __restrict__ Wv, const float* __restrict__ bv,
  const float* __restrict__ Wss, const float* __restrict__ bss,
  float* __restrict__ q, float* __restrict__ kout, float* __restrict__ vout, float* __restrict__ xr)
{
  __shared__ float xnt[32][128];
  __shared__ float Wsh[16384];
  __shared__ float red[8];
  int tid = threadIdx.x;
  int rbase = blockIdx.x * 32;
  int rr = tid >> 7, col = tid & 127;
  for (int r2 = 0; r2 < 32; r2 += 2){
    int row = rbase + r2 + rr;
    float val = (row < N_NODES) ? x[(size_t)row*128 + col] : 0.f;
    float s = val, s2 = val*val;
    #pragma unroll
    for (int sh = 32; sh >= 1; sh >>= 1){ s += __shfl_xor(s, sh, 64); s2 += __shfl_xor(s2, sh, 64); }
    int wid = tid >> 6;
    if ((tid & 63) == 0){ red[wid*2] = s; red[wid*2+1] = s2; }
    __syncthreads();
    float fs  = red[rr*4]   + red[rr*4+2];
    float fs2 = red[rr*4+1] + red[rr*4+3];
    float mean = fs * 0.0078125f;
    float var  = fs2 * 0.0078125f - mean*mean;
    float xnv = (val - mean) * rsqrtf(var + 1e-5f) * lnw[col] + lnb[col];
    xnt[r2+rr][col] = xnv;
    __syncthreads();
  }
  int c0 = (tid & 31) * 4, r0 = (tid >> 5) * 4;

  auto proj = [&](const float* __restrict__ W, const float* __restrict__ B, float* __restrict__ O){
    __syncthreads();
    for (int idx = tid; idx < 16384; idx += 256) Wsh[idx] = W[idx];
    __syncthreads();
    float acc[4][4] = {};
    for (int kk = 0; kk < 128; kk += 4){
      float4 a0 = *(const float4*)&xnt[r0+0][kk];
      float4 a1 = *(const float4*)&xnt[r0+1][kk];
      float4 a2 = *(const float4*)&xnt[r0+2][kk];
      float4 a3 = *(const float4*)&xnt[r0+3][kk];
      float4 b0 = *(const float4*)&Wsh[(kk+0)*128 + c0];
      float4 b1 = *(const float4*)&Wsh[(kk+1)*128 + c0];
      float4 b2 = *(const float4*)&Wsh[(kk+2)*128 + c0];
      float4 b3 = *(const float4*)&Wsh[(kk+3)*128 + c0];
      fma4x4(a0,a1,a2,a3,b0,b1,b2,b3,acc);
    }
    float4 bb = *(const float4*)&B[c0];
    for (int i = 0; i < 4; ++i){
      int row = rbase + r0 + i;
      if (row < N_NODES){
        float4 o;
        o.x = acc[i][0] + bb.x; o.y = acc[i][1] + bb.y;
        o.z = acc[i][2] + bb.z; o.w = acc[i][3] + bb.w;
        *(float4*)&O[(size_t)row*128 + c0] = o;
      }
    }
  };
  proj(Wq, bq, q);
  proj(Wk, bk, kout);
  proj(Wv, bv, vout);
  proj(Wss, bss, xr);
}

// ---------------- edge attention aggregation (one wave per dst node) ----------------
__global__ __launch_bounds__(256) void k_agg(
  const float* __restrict__ q, const float* __restrict__ kbuf, const float* __restrict__ vbuf,
  const float* __restrict__ edge_attr, const float* __restrict__ We, const float* __restrict__ be,
  const int* __restrict__ srcIdx, const int* __restrict__ off, const int* __restrict__ bucket,
  float* __restrict__ attn)
{
  __shared__ float WeSh[2048];
  __shared__ float beSh[128];
  int tid = threadIdx.x;
  for (int idx = tid; idx < 2048; idx += 256) WeSh[idx] = We[idx];
  if (tid < 128) beSh[tid] = be[tid];
  __syncthreads();

  int node = blockIdx.x*4 + (tid >> 6);
  int lane = tid & 63;
  int d0 = lane*2;
  float2 qv = *(const float2*)&q[(size_t)node*128 + d0];
  int beg = off[node], end = off[node+1];
  float m = -INFINITY, den = 0.f, a0 = 0.f, a1 = 0.f;
  float be0 = beSh[d0], be1 = beSh[d0+1];

  for (int p = beg; p < end; ++p){
    int eid = bucket[p];
    int src = srcIdx[eid];
    float2 kv = *(const float2*)&kbuf[(size_t)src*128 + d0];
    float2 vv = *(const float2*)&vbuf[(size_t)src*128 + d0];
    const float* ea = edge_attr + (size_t)eid*16;
    float4 e0v = *(const float4*)&ea[0];
    float4 e1v = *(const float4*)&ea[4];
    float4 e2v = *(const float4*)&ea[8];
    float4 e3v = *(const float4*)&ea[12];
    float eav[16] = {e0v.x,e0v.y,e0v.z,e0v.w, e1v.x,e1v.y,e1v.z,e1v.w,
                     e2v.x,e2v.y,e2v.z,e2v.w, e3v.x,e3v.y,e3v.z,e3v.w};
    float e0 = be0, e1 = be1;
    #pragma unroll
    for (int c = 0; c < 16; ++c){
      float2 w = *(const float2*)&WeSh[c*128 + d0];
      e0 += eav[c]*w.x; e1 += eav[c]*w.y;
    }
    float kj0 = kv.x + e0, kj1 = kv.y + e1;
    float part = qv.x*kj0 + qv.y*kj1;
    part += __shfl_xor(part, 1, 64);
    part += __shfl_xor(part, 2, 64);
    part += __shfl_xor(part, 4, 64);
    float sc = part * 0.25f;                 // /sqrt(16)
    float mn = fmaxf(m, sc);
    float corr = __expf(m - mn);             // exp(-inf)=0 on first edge
    float pe = __expf(sc - mn);
    den = den*corr + pe;
    a0 = a0*corr + pe*(vv.x + e0);
    a1 = a1*corr + pe*(vv.y + e1);
    m = mn;
  }
  float2 o = make_float2(0.f, 0.f);
  if (end > beg){ float inv = 1.0f/den; o.x = a0*inv; o.y = a1*inv; }
  *(float2*)&attn[(size_t)node*128 + d0] = o;
}

// ---------------- projection + residual: res = (attn + xr)@Wp + bp + x ----------------
__global__ __launch_bounds__(256) void k_post(
  const float* __restrict__ attn, const float* __restrict__ xr, const float* __restrict__ x,
  const float* __restrict__ Wp, const float* __restrict__ bp, float* __restrict__ res)
{
  __shared__ float at[32][128];
  __shared__ float Wsh[16384];
  int tid = threadIdx.x;
  int rbase = blockIdx.x * 32;
  for (int idx = tid; idx < 4096; idx += 256){
    int r = idx >> 7, c = idx & 127;
    int row = rbase + r;
    at[r][c] = (row < N_NODES) ? attn[(size_t)row*128 + c] + xr[(size_t)row*128 + c] : 0.f;
  }
  for (int idx = tid; idx < 16384; idx += 256) Wsh[idx] = Wp[idx];
  __syncthreads();
  int c0 = (tid & 31)*4, r0 = (tid >> 5)*4;
  float acc[4][4] = {};
  for (int kk = 0; kk < 128; kk += 4){
    float4 a0 = *(const float4*)&at[r0+0][kk];
    float4 a1 = *(const float4*)&at[r0+1][kk];
    float4 a2 = *(const float4*)&at[r0+2][kk];
    float4 a3 = *(const float4*)&at[r0+3][kk];
    float4 b0 = *(const float4*)&Wsh[(kk+0)*128 + c0];
    float4 b1 = *(const float4*)&Wsh[(kk+1)*128 + c0];
    float4 b2 = *(const float4*)&Wsh[(kk+2)*128 + c0];
    float4 b3 = *(const float4*)&Wsh[(kk+3)*128 + c0];
    fma4x4(a0,a1,a2,a3,b0,b1,b2,b3,acc);
  }
  float4 bb = *(const float4*)&bp[c0];
  for (int i = 0; i < 4; ++i){
    int row = rbase + r0 + i;
    if (row < N_NODES){
      float4 xs = *(const float4*)&x[(size_t)row*128 + c0];
      float4 o;
      o.x = acc[i][0]+bb.x+xs.x; o.y = acc[i][1]+bb.y+xs.y;
      o.z = acc[i][2]+bb.z+xs.z; o.w = acc[i][3]+bb.w+xs.w;
      *(float4*)&res[(size_t)row*128 + c0] = o;
    }
  }
}

// ---------------- MLP: out = gelu(LN(res)@W1+b1)@W2 + b2 + res ----------------
__global__ __launch_bounds__(256) void k_mlp(
  const float* __restrict__ res, const float* __restrict__ lnw, const float* __restrict__ lnb,
  const float* __restrict__ W1, const float* __restrict__ b1,
  const float* __restrict__ W2, const float* __restrict__ b2,
  float* __restrict__ out)
{
  __shared__ float ht[32][128];
  __shared__ float hid[32][512];
  __shared__ float Wsh[16384];
  __shared__ float red[8];
  int tid = threadIdx.x;
  int rbase = blockIdx.x * 32;
  int rr = tid >> 7, col = tid & 127;
  for (int r2 = 0; r2 < 32; r2 += 2){
    int row = rbase + r2 + rr;
    float val = (row < N_NODES) ? res[(size_t)row*128 + col] : 0.f;
    float s = val, s2 = val*val;
    #pragma unroll
    for (int sh = 32; sh >= 1; sh >>= 1){ s += __shfl_xor(s, sh, 64); s2 += __shfl_xor(s2, sh, 64); }
    int wid = tid >> 6;
    if ((tid & 63) == 0){ red[wid*2] = s; red[wid*2+1] = s2; }
    __syncthreads();
    float fs  = red[rr*4]   + red[rr*4+2];
    float fs2 = red[rr*4+1] + red[rr*4+3];
    float mean = fs * 0.0078125f;
    float var  = fs2 * 0.0078125f - mean*mean;
    float xnv = (val - mean)*rsqrtf(var + 1e-5f)*lnw[col] + lnb[col];
    ht[r2+rr][col] = xnv;
    __syncthreads();
  }
  int c0 = (tid & 31)*4, r0 = (tid >> 5)*4;

  // stage 1: hid = gelu(ht @ W1 + b1), col-tiles of 128
  for (int ct = 0; ct < 4; ++ct){
    __syncthreads();
    for (int idx = tid; idx < 16384; idx += 256){
      int kk2 = idx >> 7, cc = idx & 127;
      Wsh[idx] = W1[(size_t)kk2*512 + ct*128 + cc];
    }
    __syncthreads();
    float acc[4][4] = {};
    for (int kk = 0; kk < 128; kk += 4){
      float4 a0 = *(const float4*)&ht[r0+0][kk];
      float4 a1 = *(const float4*)&ht[r0+1][kk];
      float4 a2 = *(const float4*)&ht[r0+2][kk];
      float4 a3 = *(const float4*)&ht[r0+3][kk];
      float4 b0 = *(const float4*)&Wsh[(kk+0)*128 + c0];
      float4 b1v = *(const float4*)&Wsh[(kk+1)*128 + c0];
      float4 b2v = *(const float4*)&Wsh[(kk+2)*128 + c0];
      float4 b3 = *(const float4*)&Wsh[(kk+3)*128 + c0];
      fma4x4(a0,a1,a2,a3,b0,b1v,b2v,b3,acc);
    }
    float4 bb = *(const float4*)&b1[ct*128 + c0];
    for (int i = 0; i < 4; ++i){
      float4 o;
      o.x = gelu_f(acc[i][0] + bb.x);
      o.y = gelu_f(acc[i][1] + bb.y);
      o.z = gelu_f(acc[i][2] + bb.z);
      o.w = gelu_f(acc[i][3] + bb.w);
      *(float4*)&hid[r0+i][ct*128 + c0] = o;
    }
  }

  // stage 2: out = hid @ W2 + b2 + res, k-tiles of 128
  float acc2[4][4] = {};
  for (int kt = 0; kt < 4; ++kt){
    __syncthreads();
    for (int idx = tid; idx < 16384; idx += 256){
      int kk2 = idx >> 7, cc = idx & 127;
      Wsh[idx] = W2[(size_t)(kt*128 + kk2)*128 + cc];
    }
    __syncthreads();
    for (int kk = 0; kk < 128; kk += 4){
      float4 a0 = *(const float4*)&hid[r0+0][kt*128+kk];
      float4 a1 = *(const float4*)&hid[r0+1][kt*128+kk];
      float4 a2 = *(const float4*)&hid[r0+2][kt*128+kk];
      float4 a3 = *(const float4*)&hid[r0+3][kt*128+kk];
      float4 b0 = *(const float4*)&Wsh[(kk+0)*128 + c0];
      float4 b1v = *(const float4*)&Wsh[(kk+1)*128 + c0];
      float4 b2v = *(const float4*)&Wsh[(kk+2)*128 + c0];
      float4 b3 = *(const float4*)&Wsh[(kk+3)*128 + c0];
      fma4x4(a0,a1,a2,a3,b0,b1v,b2v,b3,acc2);
    }
  }
  float4 bb = *(const float4*)&b2[c0];
  for (int i = 0; i < 4; ++i){
    int row = rbase + r0 + i;
    if (row < N_NODES){
      float4 rs = *(const float4*)&res[(size_t)row*128 + c0];
      float4 o;
      o.x = acc2[i][0]+bb.x+rs.x; o.y = acc2[i][1]+bb.y+rs.y;
      o.z = acc2[i][2]+bb.z+rs.z; o.w = acc2[i][3]+bb.w+rs.w;
      *(float4*)&out[(size_t)row*128 + c0] = o;
    }
  }
}

extern "C" void kernel_launch(void* const* d_in, const int* in_sizes, int n_in,
                              void* d_out, int out_size, void* d_ws, size_t ws_size,
                              hipStream_t stream)
{
  const float* x        = (const float*)d_in[0];
  const float* edge_attr= (const float*)d_in[1];
  const int*   edge_index=(const int*)d_in[2];
  const float* Wq = (const float*)d_in[3];  const float* bq = (const float*)d_in[4];
  const float* Wk = (const float*)d_in[5];  const float* bk = (const float*)d_in[6];
  const float* Wv = (const float*)d_in[7];  const float* bv = (const float*)d_in[8];
  const float* Wss= (const float*)d_in[9];  const float* bss= (const float*)d_in[10];
  const float* We = (const float*)d_in[11]; const float* be = (const float*)d_in[12];
  const float* Wp = (const float*)d_in[13]; const float* bp = (const float*)d_in[14];
  const float* lnaw=(const float*)d_in[15]; const float* lnab=(const float*)d_in[16];
  const float* lnmw=(const float*)d_in[17]; const float* lnmb=(const float*)d_in[18];
  const float* W1 = (const float*)d_in[19]; const float* b1 = (const float*)d_in[20];
  const float* W2 = (const float*)d_in[21]; const float* b2 = (const float*)d_in[22];

  float* ws   = (float*)d_ws;
  float* q    = ws;
  float* kbuf = ws + 6400000;
  float* vbuf = ws + 12800000;
  float* xr   = ws + 19200000;
  float* attn = ws + 25600000;
  float* res  = q;                         // q dead after k_agg
  int*   iw   = (int*)(ws + 32000000);
  int* deg    = iw;                        // N
  int* off    = iw + 50000;                // N+1
  int* cursor = iw + 100001;               // N
  int* bucket = iw + 150001;               // E

  const int* srcIdx = edge_index;
  const int* dstIdx = edge_index + N_EDGES;

  hipMemsetAsync(deg, 0, N_NODES*sizeof(int), stream);
  k_deg<<<(N_EDGES+255)/256, 256, 0, stream>>>(dstIdx, deg);
  k_scan<<<1, 1024, 0, stream>>>(deg, off, cursor);
  k_scatter<<<(N_EDGES+255)/256, 256, 0, stream>>>(dstIdx, cursor, bucket);
  k_nodeproj<<<(N_NODES+31)/32, 256, 0, stream>>>(x, lnaw, lnab, Wq,bq, Wk,bk, Wv,bv, Wss,bss,
                                                  q, kbuf, vbuf, xr);
  k_agg<<<N_NODES/4, 256, 0, stream>>>(q, kbuf, vbuf, edge_attr, We, be,
                                       srcIdx, off, bucket, attn);
  k_post<<<(N_NODES+31)/32, 256, 0, stream>>>(attn, xr, x, Wp, bp, res);
  k_mlp<<<(N_NODES+31)/32, 256, 0, stream>>>(res, lnmw, lnmb, W1, b1, W2, b2, (float*)d_out);
  hipMemcpyAsync((float*)d_out + (size_t)N_NODES*128, edge_attr,
                 (size_t)N_EDGES*16*sizeof(float), hipMemcpyDeviceToDevice, stream);
}

// Round 2
// 627.837 us; speedup vs baseline: 2.0354x; 2.0354x over previous
//
#include <hip/hip_runtime.h>
#include <math.h>

#define N_NODES 50000
#define N_EDGES 800000

typedef __attribute__((ext_vector_type(8))) short bf16x8;
typedef __attribute__((ext_vector_type(4))) float f32x4;

__device__ __forceinline__ short f2bf(float f){
  unsigned u = __float_as_uint(f);
  unsigned r = (u + 0x7FFFu + ((u >> 16) & 1u)) >> 16;
  return (short)r;
}

__device__ __forceinline__ float gelu_f(float x){
  float z = 0.7978845608028654f*(x + 0.044715f*x*x*x);
  float e = __expf(2.0f*z);
  return 0.5f*x*(2.0f - 2.0f/(e + 1.0f));   // 0.5x(1+tanh z), inf-safe
}

// ---------------- weight transpose + bf16 convert: Wt[n][k] = bf16(W[k][n]) ----------------
__global__ __launch_bounds__(256) void k_tconv(const float* __restrict__ W, short* __restrict__ Wt,
                                               int K, int Nn){
  int i = blockIdx.x*256 + threadIdx.x;
  if (i < K*Nn){
    int n = i / K, k = i - n*K;
    Wt[(size_t)n*K + k] = f2bf(W[(size_t)k*Nn + n]);
  }
}

// ---------------- CSR build ----------------
__global__ __launch_bounds__(256) void k_deg(const int* __restrict__ dst, int* __restrict__ deg){
  int i = blockIdx.x*256 + threadIdx.x;
  if (i < N_EDGES) atomicAdd(&deg[dst[i]], 1);
}

__global__ __launch_bounds__(1024) void k_scan(const int* __restrict__ deg,
                                               int* __restrict__ off, int* __restrict__ cursor){
  __shared__ int wsum[16];
  __shared__ int chunk_total;
  __shared__ int carry;
  int tid = threadIdx.x, lane = tid & 63, wid = tid >> 6;
  if (tid == 0) carry = 0;
  __syncthreads();
  for (int base = 0; base < N_NODES; base += 1024){
    int i = base + tid;
    int val = (i < N_NODES) ? deg[i] : 0;
    int incl = val;
    #pragma unroll
    for (int s = 1; s < 64; s <<= 1){
      int t = __shfl_up(incl, s, 64);
      if (lane >= s) incl += t;
    }
    if (lane == 63) wsum[wid] = incl;
    __syncthreads();
    if (tid < 16){
      int t = wsum[tid];
      int inc = t;
      #pragma unroll
      for (int s = 1; s < 16; s <<= 1){
        int u = __shfl_up(inc, s, 64);
        if (tid >= s) inc += u;
      }
      wsum[tid] = inc - t;
      if (tid == 15) chunk_total = inc;
    }
    __syncthreads();
    int excl = carry + wsum[wid] + (incl - val);
    if (i < N_NODES){ off[i] = excl; cursor[i] = excl; }
    __syncthreads();
    if (tid == 0) carry += chunk_total;
    __syncthreads();
  }
  if (threadIdx.x == 0) off[N_NODES] = carry;
}

__global__ __launch_bounds__(256) void k_scatter(const int* __restrict__ dst,
                                                 int* __restrict__ cursor, int* __restrict__ bucket){
  int i = blockIdx.x*256 + threadIdx.x;
  if (i < N_EDGES){
    int d = dst[i];
    int pos = atomicAdd(&cursor[d], 1);
    bucket[pos] = i;
  }
}

// ---------------- node projections: LN(x) -> q,k,v,x_r (bf16 MFMA) ----------------
__global__ __launch_bounds__(256) void k_nodeproj(
  const float* __restrict__ x, const float* __restrict__ lnw, const float* __restrict__ lnb,
  const short* __restrict__ Wtq, const short* __restrict__ Wtk,
  const short* __restrict__ Wtv, const short* __restrict__ Wts,
  const float* __restrict__ bq, const float* __restrict__ bk,
  const float* __restrict__ bv, const float* __restrict__ bs,
  float* __restrict__ q, float* __restrict__ kout, float* __restrict__ vout, float* __restrict__ xr)
{
  __shared__ short A[64][136];
  int tid = threadIdx.x;
  int rbase = blockIdx.x * 64;

  // LN phase: 4 threads per row, 32 cols each
  {
    int r = tid >> 2, j = tid & 3;
    int row = rbase + r;
    bool ok = row < N_NODES;
    const float* xp = x + (size_t)row*128 + j*32;
    float vals[32];
    #pragma unroll
    for (int i = 0; i < 8; ++i){
      float4 t = ok ? *(const float4*)(xp + i*4) : make_float4(0,0,0,0);
      vals[i*4+0]=t.x; vals[i*4+1]=t.y; vals[i*4+2]=t.z; vals[i*4+3]=t.w;
    }
    float s = 0.f, s2 = 0.f;
    #pragma unroll
    for (int i = 0; i < 32; ++i){ s += vals[i]; s2 += vals[i]*vals[i]; }
    s  += __shfl_xor(s, 1, 64);  s  += __shfl_xor(s, 2, 64);
    s2 += __shfl_xor(s2, 1, 64); s2 += __shfl_xor(s2, 2, 64);
    float mean = s * 0.0078125f;
    float var  = s2 * 0.0078125f - mean*mean;
    float rstd = rsqrtf(var + 1e-5f);
    #pragma unroll
    for (int i = 0; i < 32; ++i){
      int col = j*32 + i;
      float xn = (vals[i]-mean)*rstd*lnw[col] + lnb[col];
      A[r][col] = f2bf(xn);
    }
  }
  __syncthreads();

  int lane = tid & 63, wave = tid >> 6;
  int row16 = lane & 15, kg = lane >> 4;
  int cb = wave * 32;

  auto gemm = [&](const short* __restrict__ B, const float* __restrict__ bias, float* __restrict__ O){
    f32x4 acc[4][2] = {};
    #pragma unroll
    for (int kk = 0; kk < 128; kk += 32){
      int k0 = kk + kg*8;
      bf16x8 a0 = *(const bf16x8*)&A[ 0 + row16][k0];
      bf16x8 a1 = *(const bf16x8*)&A[16 + row16][k0];
      bf16x8 a2 = *(const bf16x8*)&A[32 + row16][k0];
      bf16x8 a3 = *(const bf16x8*)&A[48 + row16][k0];
      bf16x8 b0 = *(const bf16x8*)&B[(size_t)(cb +      row16)*128 + k0];
      bf16x8 b1 = *(const bf16x8*)&B[(size_t)(cb + 16 + row16)*128 + k0];
      acc[0][0] = __builtin_amdgcn_mfma_f32_16x16x32_bf16(a0, b0, acc[0][0], 0,0,0);
      acc[1][0] = __builtin_amdgcn_mfma_f32_16x16x32_bf16(a1, b0, acc[1][0], 0,0,0);
      acc[2][0] = __builtin_amdgcn_mfma_f32_16x16x32_bf16(a2, b0, acc[2][0], 0,0,0);
      acc[3][0] = __builtin_amdgcn_mfma_f32_16x16x32_bf16(a3, b0, acc[3][0], 0,0,0);
      acc[0][1] = __builtin_amdgcn_mfma_f32_16x16x32_bf16(a0, b1, acc[0][1], 0,0,0);
      acc[1][1] = __builtin_amdgcn_mfma_f32_16x16x32_bf16(a1, b1, acc[1][1], 0,0,0);
      acc[2][1] = __builtin_amdgcn_mfma_f32_16x16x32_bf16(a2, b1, acc[2][1], 0,0,0);
      acc[3][1] = __builtin_amdgcn_mfma_f32_16x16x32_bf16(a3, b1, acc[3][1], 0,0,0);
    }
    float bv0 = bias[cb + row16], bv1 = bias[cb + 16 + row16];
    #pragma unroll
    for (int rt = 0; rt < 4; ++rt){
      int rowb = rbase + rt*16 + kg*4;
      #pragma unroll
      for (int i = 0; i < 4; ++i){
        int row = rowb + i;
        if (row < N_NODES){
          O[(size_t)row*128 + cb      + row16] = acc[rt][0][i] + bv0;
          O[(size_t)row*128 + cb + 16 + row16] = acc[rt][1][i] + bv1;
        }
      }
    }
  };
  gemm(Wtq, bq, q);
  gemm(Wtk, bk, kout);
  gemm(Wtv, bv, vout);
  gemm(Wts, bs, xr);
}

// ---------------- edge attention aggregation (one wave per dst node), out += into xr ----------------
__global__ __launch_bounds__(256) void k_agg(
  const float* __restrict__ q, const float* __restrict__ kbuf, const float* __restrict__ vbuf,
  const float* __restrict__ edge_attr, const float* __restrict__ We, const float* __restrict__ be,
  const int* __restrict__ srcIdx, const int* __restrict__ off, const int* __restrict__ bucket,
  float* __restrict__ xr)
{
  __shared__ float WeSh[2048];
  __shared__ float beSh[128];
  int tid = threadIdx.x;
  for (int idx = tid; idx < 2048; idx += 256) WeSh[idx] = We[idx];
  if (tid < 128) beSh[tid] = be[tid];
  __syncthreads();

  int node = blockIdx.x*4 + (tid >> 6);
  int lane = tid & 63;
  int d0 = lane*2;
  float2 qv = *(const float2*)&q[(size_t)node*128 + d0];
  int beg = off[node], end = off[node+1];
  float m = -INFINITY, den = 0.f, a0 = 0.f, a1 = 0.f;
  float be0 = beSh[d0], be1 = beSh[d0+1];

  for (int p = beg; p < end; ++p){
    int eid = bucket[p];
    int src = srcIdx[eid];
    float2 kv = *(const float2*)&kbuf[(size_t)src*128 + d0];
    float2 vv = *(const float2*)&vbuf[(size_t)src*128 + d0];
    const float* ea = edge_attr + (size_t)eid*16;
    float4 e0v = *(const float4*)&ea[0];
    float4 e1v = *(const float4*)&ea[4];
    float4 e2v = *(const float4*)&ea[8];
    float4 e3v = *(const float4*)&ea[12];
    float eav[16] = {e0v.x,e0v.y,e0v.z,e0v.w, e1v.x,e1v.y,e1v.z,e1v.w,
                     e2v.x,e2v.y,e2v.z,e2v.w, e3v.x,e3v.y,e3v.z,e3v.w};
    float e0 = be0, e1 = be1;
    #pragma unroll
    for (int c = 0; c < 16; ++c){
      float2 w = *(const float2*)&WeSh[c*128 + d0];
      e0 += eav[c]*w.x; e1 += eav[c]*w.y;
    }
    float kj0 = kv.x + e0, kj1 = kv.y + e1;
    float part = qv.x*kj0 + qv.y*kj1;
    part += __shfl_xor(part, 1, 64);
    part += __shfl_xor(part, 2, 64);
    part += __shfl_xor(part, 4, 64);
    float sc = part * 0.25f;
    float mn = fmaxf(m, sc);
    float corr = __expf(m - mn);
    float pe = __expf(sc - mn);
    den = den*corr + pe;
    a0 = a0*corr + pe*(vv.x + e0);
    a1 = a1*corr + pe*(vv.y + e1);
    m = mn;
  }
  float2 xv = *(const float2*)&xr[(size_t)node*128 + d0];
  float2 o = xv;
  if (end > beg){ float inv = 1.0f/den; o.x += a0*inv; o.y += a1*inv; }
  *(float2*)&xr[(size_t)node*128 + d0] = o;
}

// ---------------- post: res = (aggout)@Wp + bp + x ; A2 = bf16(LN(res)) ----------------
__global__ __launch_bounds__(256) void k_post(
  const float* __restrict__ aggout, const float* __restrict__ x,
  const short* __restrict__ Wtp, const float* __restrict__ bp,
  const float* __restrict__ lnw, const float* __restrict__ lnb,
  float* __restrict__ res, short* __restrict__ A2)
{
  __shared__ short A[64][136];
  __shared__ float rf[64][132];
  int tid = threadIdx.x;
  int rbase = blockIdx.x * 64;

  // phase 1: A = bf16(aggout)
  {
    int r = tid >> 2, j = tid & 3;
    int row = rbase + r;
    const float* p = aggout + (size_t)row*128 + j*32;
    #pragma unroll
    for (int i = 0; i < 8; ++i){
      float4 t = *(const float4*)(p + i*4);
      int c = j*32 + i*4;
      A[r][c+0] = f2bf(t.x); A[r][c+1] = f2bf(t.y);
      A[r][c+2] = f2bf(t.z); A[r][c+3] = f2bf(t.w);
    }
  }
  __syncthreads();

  int lane = tid & 63, wave = tid >> 6;
  int row16 = lane & 15, kg = lane >> 4;
  int cb = wave * 32;

  f32x4 acc[4][2] = {};
  #pragma unroll
  for (int kk = 0; kk < 128; kk += 32){
    int k0 = kk + kg*8;
    bf16x8 a0 = *(const bf16x8*)&A[ 0 + row16][k0];
    bf16x8 a1 = *(const bf16x8*)&A[16 + row16][k0];
    bf16x8 a2 = *(const bf16x8*)&A[32 + row16][k0];
    bf16x8 a3 = *(const bf16x8*)&A[48 + row16][k0];
    bf16x8 b0 = *(const bf16x8*)&Wtp[(size_t)(cb +      row16)*128 + k0];
    bf16x8 b1 = *(const bf16x8*)&Wtp[(size_t)(cb + 16 + row16)*128 + k0];
    acc[0][0] = __builtin_amdgcn_mfma_f32_16x16x32_bf16(a0, b0, acc[0][0], 0,0,0);
    acc[1][0] = __builtin_amdgcn_mfma_f32_16x16x32_bf16(a1, b0, acc[1][0], 0,0,0);
    acc[2][0] = __builtin_amdgcn_mfma_f32_16x16x32_bf16(a2, b0, acc[2][0], 0,0,0);
    acc[3][0] = __builtin_amdgcn_mfma_f32_16x16x32_bf16(a3, b0, acc[3][0], 0,0,0);
    acc[0][1] = __builtin_amdgcn_mfma_f32_16x16x32_bf16(a0, b1, acc[0][1], 0,0,0);
    acc[1][1] = __builtin_amdgcn_mfma_f32_16x16x32_bf16(a1, b1, acc[1][1], 0,0,0);
    acc[2][1] = __builtin_amdgcn_mfma_f32_16x16x32_bf16(a2, b1, acc[2][1], 0,0,0);
    acc[3][1] = __builtin_amdgcn_mfma_f32_16x16x32_bf16(a3, b1, acc[3][1], 0,0,0);
  }
  float bv0 = bp[cb + row16], bv1 = bp[cb + 16 + row16];
  #pragma unroll
  for (int rt = 0; rt < 4; ++rt){
    #pragma unroll
    for (int i = 0; i < 4; ++i){
      int rl = rt*16 + kg*4 + i;
      int row = rbase + rl;
      float v0 = acc[rt][0][i] + bv0;
      float v1 = acc[rt][1][i] + bv1;
      if (row < N_NODES){
        v0 += x[(size_t)row*128 + cb      + row16];
        v1 += x[(size_t)row*128 + cb + 16 + row16];
        res[(size_t)row*128 + cb      + row16] = v0;
        res[(size_t)row*128 + cb + 16 + row16] = v1;
      }
      rf[rl][cb      + row16] = v0;
      rf[rl][cb + 16 + row16] = v1;
    }
  }
  __syncthreads();

  // phase 4: LN over rf -> A2 (bf16), stored for all 64 rows
  {
    int r = tid >> 2, j = tid & 3;
    int row = rbase + r;
    float vals[32];
    #pragma unroll
    for (int i = 0; i < 8; ++i){
      float4 t = *(const float4*)&rf[r][j*32 + i*4];
      vals[i*4+0]=t.x; vals[i*4+1]=t.y; vals[i*4+2]=t.z; vals[i*4+3]=t.w;
    }
    float s = 0.f, s2 = 0.f;
    #pragma unroll
    for (int i = 0; i < 32; ++i){ s += vals[i]; s2 += vals[i]*vals[i]; }
    s  += __shfl_xor(s, 1, 64);  s  += __shfl_xor(s, 2, 64);
    s2 += __shfl_xor(s2, 1, 64); s2 += __shfl_xor(s2, 2, 64);
    float mean = s * 0.0078125f;
    float var  = s2 * 0.0078125f - mean*mean;
    float rstd = rsqrtf(var + 1e-5f);
    #pragma unroll
    for (int i = 0; i < 32; ++i){
      int col = j*32 + i;
      float xn = (vals[i]-mean)*rstd*lnw[col] + lnb[col];
      A2[(size_t)row*128 + col] = f2bf(xn);
    }
  }
}

// ---------------- mlp1: hid = bf16(gelu(A2 @ W1 + b1)) ----------------
__global__ __launch_bounds__(256) void k_mlp1(
  const short* __restrict__ A2, const short* __restrict__ W1t, const float* __restrict__ b1,
  short* __restrict__ hid)
{
  __shared__ short A[64][136];
  int tid = threadIdx.x;
  int rbase = blockIdx.x * 64;
  int ch = blockIdx.y;
  for (int idx = tid; idx < 1024; idx += 256){
    int r = idx >> 4, g = idx & 15;
    *(uint4*)&A[r][g*8] = *(const uint4*)&A2[((size_t)(rbase + r))*128 + g*8];
  }
  __syncthreads();

  int lane = tid & 63, wave = tid >> 6;
  int row16 = lane & 15, kg = lane >> 4;
  int cb = ch*256 + wave*64;

  f32x4 acc[4][4] = {};
  #pragma unroll
  for (int kk = 0; kk < 128; kk += 32){
    int k0 = kk + kg*8;
    bf16x8 a[4], b[4];
    #pragma unroll
    for (int rt = 0; rt < 4; ++rt) a[rt] = *(const bf16x8*)&A[rt*16 + row16][k0];
    #pragma unroll
    for (int ct = 0; ct < 4; ++ct) b[ct] = *(const bf16x8*)&W1t[(size_t)(cb + ct*16 + row16)*128 + k0];
    #pragma unroll
    for (int rt = 0; rt < 4; ++rt)
      #pragma unroll
      for (int ct = 0; ct < 4; ++ct)
        acc[rt][ct] = __builtin_amdgcn_mfma_f32_16x16x32_bf16(a[rt], b[ct], acc[rt][ct], 0,0,0);
  }
  float bv[4];
  #pragma unroll
  for (int ct = 0; ct < 4; ++ct) bv[ct] = b1[cb + ct*16 + row16];
  #pragma unroll
  for (int rt = 0; rt < 4; ++rt){
    #pragma unroll
    for (int ct = 0; ct < 4; ++ct){
      #pragma unroll
      for (int i = 0; i < 4; ++i){
        int row = rbase + rt*16 + kg*4 + i;
        hid[(size_t)row*512 + cb + ct*16 + row16] = f2bf(gelu_f(acc[rt][ct][i] + bv[ct]));
      }
    }
  }
}

// ---------------- mlp2: out = hid @ W2 + b2 + res ----------------
__global__ __launch_bounds__(256) void k_mlp2(
  const short* __restrict__ hid, const short* __restrict__ W2t, const float* __restrict__ b2,
  const float* __restrict__ res, float* __restrict__ out)
{
  __shared__ short A[64][136];
  int tid = threadIdx.x;
  int rbase = blockIdx.x * 64;
  int lane = tid & 63, wave = tid >> 6;
  int row16 = lane & 15, kg = lane >> 4;
  int cb = wave * 32;

  f32x4 acc[4][2] = {};
  for (int kc = 0; kc < 4; ++kc){
    __syncthreads();
    for (int idx = tid; idx < 1024; idx += 256){
      int r = idx >> 4, g = idx & 15;
      *(uint4*)&A[r][g*8] = *(const uint4*)&hid[((size_t)(rbase + r))*512 + kc*128 + g*8];
    }
    __syncthreads();
    #pragma unroll
    for (int kk = 0; kk < 128; kk += 32){
      int k0 = kk + kg*8;
      bf16x8 a0 = *(const bf16x8*)&A[ 0 + row16][k0];
      bf16x8 a1 = *(const bf16x8*)&A[16 + row16][k0];
      bf16x8 a2 = *(const bf16x8*)&A[32 + row16][k0];
      bf16x8 a3 = *(const bf16x8*)&A[48 + row16][k0];
      bf16x8 b0 = *(const bf16x8*)&W2t[(size_t)(cb +      row16)*512 + kc*128 + k0];
      bf16x8 b1 = *(const bf16x8*)&W2t[(size_t)(cb + 16 + row16)*512 + kc*128 + k0];
      acc[0][0] = __builtin_amdgcn_mfma_f32_16x16x32_bf16(a0, b0, acc[0][0], 0,0,0);
      acc[1][0] = __builtin_amdgcn_mfma_f32_16x16x32_bf16(a1, b0, acc[1][0], 0,0,0);
      acc[2][0] = __builtin_amdgcn_mfma_f32_16x16x32_bf16(a2, b0, acc[2][0], 0,0,0);
      acc[3][0] = __builtin_amdgcn_mfma_f32_16x16x32_bf16(a3, b0, acc[3][0], 0,0,0);
      acc[0][1] = __builtin_amdgcn_mfma_f32_16x16x32_bf16(a0, b1, acc[0][1], 0,0,0);
      acc[1][1] = __builtin_amdgcn_mfma_f32_16x16x32_bf16(a1, b1, acc[1][1], 0,0,0);
      acc[2][1] = __builtin_amdgcn_mfma_f32_16x16x32_bf16(a2, b1, acc[2][1], 0,0,0);
      acc[3][1] = __builtin_amdgcn_mfma_f32_16x16x32_bf16(a3, b1, acc[3][1], 0,0,0);
    }
  }
  float bv0 = b2[cb + row16], bv1 = b2[cb + 16 + row16];
  #pragma unroll
  for (int rt = 0; rt < 4; ++rt){
    #pragma unroll
    for (int i = 0; i < 4; ++i){
      int row = rbase + rt*16 + kg*4 + i;
      if (row < N_NODES){
        out[(size_t)row*128 + cb      + row16] = acc[rt][0][i] + bv0 + res[(size_t)row*128 + cb      + row16];
        out[(size_t)row*128 + cb + 16 + row16] = acc[rt][1][i] + bv1 + res[(size_t)row*128 + cb + 16 + row16];
      }
    }
  }
}

extern "C" void kernel_launch(void* const* d_in, const int* in_sizes, int n_in,
                              void* d_out, int out_size, void* d_ws, size_t ws_size,
                              hipStream_t stream)
{
  const float* x        = (const float*)d_in[0];
  const float* edge_attr= (const float*)d_in[1];
  const int*   edge_index=(const int*)d_in[2];
  const float* Wq = (const float*)d_in[3];  const float* bq = (const float*)d_in[4];
  const float* Wk = (const float*)d_in[5];  const float* bk = (const float*)d_in[6];
  const float* Wv = (const float*)d_in[7];  const float* bv = (const float*)d_in[8];
  const float* Wss= (const float*)d_in[9];  const float* bss= (const float*)d_in[10];
  const float* We = (const float*)d_in[11]; const float* be = (const float*)d_in[12];
  const float* Wp = (const float*)d_in[13]; const float* bp = (const float*)d_in[14];
  const float* lnaw=(const float*)d_in[15]; const float* lnab=(const float*)d_in[16];
  const float* lnmw=(const float*)d_in[17]; const float* lnmb=(const float*)d_in[18];
  const float* W1 = (const float*)d_in[19]; const float* b1 = (const float*)d_in[20];
  const float* W2 = (const float*)d_in[21]; const float* b2 = (const float*)d_in[22];

  float* ws = (float*)d_ws;
  // N_PAD = 50048 rows; each f32 [N_PAD][128] buffer = 6,406,144 floats
  float* q    = ws;                        // -> later reused as res
  float* kbuf = ws + 6406144;              // -> later reused as A2 (bf16)
  float* vbuf = ws + 12812288;             // vbuf+xr region -> later hid (bf16 [N_PAD][512])
  float* xr   = ws + 19218432;             // agg output accumulates here
  short* wts  = (short*)(ws + 25624576);
  short* Wtq  = wts;
  short* Wtk  = wts + 16384;
  short* Wtv  = wts + 32768;
  short* Wts_ = wts + 49152;
  short* Wtp  = wts + 65536;
  short* W1t  = wts + 81920;               // [512][128]
  short* W2t  = wts + 147456;              // [128][512]
  int*   iw   = (int*)(ws + 25624576 + 106496);
  int* deg    = iw;
  int* off    = iw + 50000;
  int* cursor = iw + 100001;
  int* bucket = iw + 150001;

  float* res  = q;
  short* A2   = (short*)kbuf;
  short* hid  = (short*)vbuf;

  const int* srcIdx = edge_index;
  const int* dstIdx = edge_index + N_EDGES;

  // weight prep
  k_tconv<<<64,  256, 0, stream>>>(Wq,  Wtq, 128, 128);
  k_tconv<<<64,  256, 0, stream>>>(Wk,  Wtk, 128, 128);
  k_tconv<<<64,  256, 0, stream>>>(Wv,  Wtv, 128, 128);
  k_tconv<<<64,  256, 0, stream>>>(Wss, Wts_,128, 128);
  k_tconv<<<64,  256, 0, stream>>>(Wp,  Wtp, 128, 128);
  k_tconv<<<256, 256, 0, stream>>>(W1,  W1t, 128, 512);
  k_tconv<<<256, 256, 0, stream>>>(W2,  W2t, 512, 128);

  // CSR
  hipMemsetAsync(deg, 0, N_NODES*sizeof(int), stream);
  k_deg<<<(N_EDGES+255)/256, 256, 0, stream>>>(dstIdx, deg);
  k_scan<<<1, 1024, 0, stream>>>(deg, off, cursor);
  k_scatter<<<(N_EDGES+255)/256, 256, 0, stream>>>(dstIdx, cursor, bucket);

  // main pipeline
  k_nodeproj<<<782, 256, 0, stream>>>(x, lnaw, lnab, Wtq, Wtk, Wtv, Wts_,
                                      bq, bk, bv, bss, q, kbuf, vbuf, xr);
  k_agg<<<N_NODES/4, 256, 0, stream>>>(q, kbuf, vbuf, edge_attr, We, be,
                                       srcIdx, off, bucket, xr);
  k_post<<<782, 256, 0, stream>>>(xr, x, Wtp, bp, lnmw, lnmb, res, A2);
  k_mlp1<<<dim3(782,2), 256, 0, stream>>>(A2, W1t, b1, hid);
  k_mlp2<<<782, 256, 0, stream>>>(hid, W2t, b2, res, (float*)d_out);

  hipMemcpyAsync((float*)d_out + (size_t)N_NODES*128, edge_attr,
                 (size_t)N_EDGES*16*sizeof(float), hipMemcpyDeviceToDevice, stream);
}

// Round 4
// 426.906 us; speedup vs baseline: 2.9934x; 1.4707x over previous
//
#include <hip/hip_runtime.h>
#include <math.h>

#define N_NODES 50000
#define N_EDGES 800000

typedef __attribute__((ext_vector_type(8))) short bf16x8;
typedef __attribute__((ext_vector_type(4))) float f32x4;

__device__ __forceinline__ short f2bf(float f){
  unsigned u = __float_as_uint(f);
  unsigned r = (u + 0x7FFFu + ((u >> 16) & 1u)) >> 16;
  return (short)r;
}

__device__ __forceinline__ float gelu_f(float x){
  float z = 0.7978845608028654f*(x + 0.044715f*x*x*x);
  float e = __expf(2.0f*z);
  return 0.5f*x*(2.0f - 2.0f/(e + 1.0f));   // 0.5x(1+tanh z), inf-safe
}

// ---------------- weight transpose + bf16 convert: Wt[n][k] = bf16(W[k][n]) ----------------
__global__ __launch_bounds__(256) void k_tconv(const float* __restrict__ W, short* __restrict__ Wt,
                                               int K, int Nn){
  int i = blockIdx.x*256 + threadIdx.x;
  if (i < K*Nn){
    int n = i / K, k = i - n*K;
    Wt[(size_t)n*K + k] = f2bf(W[(size_t)k*Nn + n]);
  }
}

// ---------------- CSR build ----------------
__global__ __launch_bounds__(256) void k_deg(const int* __restrict__ dst, int* __restrict__ deg){
  int i = blockIdx.x*256 + threadIdx.x;
  if (i < N_EDGES) atomicAdd(&deg[dst[i]], 1);
}

__global__ __launch_bounds__(1024) void k_scan(const int* __restrict__ deg,
                                               int* __restrict__ off, int* __restrict__ cursor){
  __shared__ int wsum[16];
  __shared__ int chunk_total;
  __shared__ int carry;
  int tid = threadIdx.x, lane = tid & 63, wid = tid >> 6;
  if (tid == 0) carry = 0;
  __syncthreads();
  for (int base = 0; base < N_NODES; base += 1024){
    int i = base + tid;
    int val = (i < N_NODES) ? deg[i] : 0;
    int incl = val;
    #pragma unroll
    for (int s = 1; s < 64; s <<= 1){
      int t = __shfl_up(incl, s, 64);
      if (lane >= s) incl += t;
    }
    if (lane == 63) wsum[wid] = incl;
    __syncthreads();
    if (tid < 16){
      int t = wsum[tid];
      int inc = t;
      #pragma unroll
      for (int s = 1; s < 16; s <<= 1){
        int u = __shfl_up(inc, s, 64);
        if (tid >= s) inc += u;
      }
      wsum[tid] = inc - t;
      if (tid == 15) chunk_total = inc;
    }
    __syncthreads();
    int excl = carry + wsum[wid] + (incl - val);
    if (i < N_NODES){ off[i] = excl; cursor[i] = excl; }
    __syncthreads();
    if (tid == 0) carry += chunk_total;
    __syncthreads();
  }
  if (threadIdx.x == 0) off[N_NODES] = carry;
}

__global__ __launch_bounds__(256) void k_scatter(const int* __restrict__ dst,
                                                 int* __restrict__ cursor, int* __restrict__ bucket){
  int i = blockIdx.x*256 + threadIdx.x;
  if (i < N_EDGES){
    int d = dst[i];
    int pos = atomicAdd(&cursor[d], 1);
    bucket[pos] = i;
  }
}

// ---------------- node projections: LN(x) -> q(f32), k(bf16), v(bf16), x_r(f32) ----------------
__global__ __launch_bounds__(256) void k_nodeproj(
  const float* __restrict__ x, const float* __restrict__ lnw, const float* __restrict__ lnb,
  const short* __restrict__ Wtq, const short* __restrict__ Wtk,
  const short* __restrict__ Wtv, const short* __restrict__ Wts,
  const float* __restrict__ bq, const float* __restrict__ bk,
  const float* __restrict__ bv, const float* __restrict__ bs,
  float* __restrict__ q, ushort* __restrict__ kb, ushort* __restrict__ vb, float* __restrict__ xr)
{
  __shared__ short A[64][136];
  int tid = threadIdx.x;
  int rbase = blockIdx.x * 64;

  // LN phase: 4 threads per row, 32 cols each
  {
    int r = tid >> 2, j = tid & 3;
    int row = rbase + r;
    bool ok = row < N_NODES;
    const float* xp = x + (size_t)row*128 + j*32;
    float vals[32];
    #pragma unroll
    for (int i = 0; i < 8; ++i){
      float4 t = ok ? *(const float4*)(xp + i*4) : make_float4(0,0,0,0);
      vals[i*4+0]=t.x; vals[i*4+1]=t.y; vals[i*4+2]=t.z; vals[i*4+3]=t.w;
    }
    float s = 0.f, s2 = 0.f;
    #pragma unroll
    for (int i = 0; i < 32; ++i){ s += vals[i]; s2 += vals[i]*vals[i]; }
    s  += __shfl_xor(s, 1, 64);  s  += __shfl_xor(s, 2, 64);
    s2 += __shfl_xor(s2, 1, 64); s2 += __shfl_xor(s2, 2, 64);
    float mean = s * 0.0078125f;
    float var  = s2 * 0.0078125f - mean*mean;
    float rstd = rsqrtf(var + 1e-5f);
    #pragma unroll
    for (int i = 0; i < 32; ++i){
      int col = j*32 + i;
      float xn = (vals[i]-mean)*rstd*lnw[col] + lnb[col];
      A[r][col] = f2bf(xn);
    }
  }
  __syncthreads();

  int lane = tid & 63, wave = tid >> 6;
  int row16 = lane & 15, kg = lane >> 4;
  int cb = wave * 32;

  auto gemm = [&](const short* __restrict__ B, const float* __restrict__ bias,
                  float* __restrict__ Of, ushort* __restrict__ Ob){
    f32x4 acc[4][2] = {};
    #pragma unroll
    for (int kk = 0; kk < 128; kk += 32){
      int k0 = kk + kg*8;
      bf16x8 a0 = *(const bf16x8*)&A[ 0 + row16][k0];
      bf16x8 a1 = *(const bf16x8*)&A[16 + row16][k0];
      bf16x8 a2 = *(const bf16x8*)&A[32 + row16][k0];
      bf16x8 a3 = *(const bf16x8*)&A[48 + row16][k0];
      bf16x8 b0 = *(const bf16x8*)&B[(size_t)(cb +      row16)*128 + k0];
      bf16x8 b1 = *(const bf16x8*)&B[(size_t)(cb + 16 + row16)*128 + k0];
      acc[0][0] = __builtin_amdgcn_mfma_f32_16x16x32_bf16(a0, b0, acc[0][0], 0,0,0);
      acc[1][0] = __builtin_amdgcn_mfma_f32_16x16x32_bf16(a1, b0, acc[1][0], 0,0,0);
      acc[2][0] = __builtin_amdgcn_mfma_f32_16x16x32_bf16(a2, b0, acc[2][0], 0,0,0);
      acc[3][0] = __builtin_amdgcn_mfma_f32_16x16x32_bf16(a3, b0, acc[3][0], 0,0,0);
      acc[0][1] = __builtin_amdgcn_mfma_f32_16x16x32_bf16(a0, b1, acc[0][1], 0,0,0);
      acc[1][1] = __builtin_amdgcn_mfma_f32_16x16x32_bf16(a1, b1, acc[1][1], 0,0,0);
      acc[2][1] = __builtin_amdgcn_mfma_f32_16x16x32_bf16(a2, b1, acc[2][1], 0,0,0);
      acc[3][1] = __builtin_amdgcn_mfma_f32_16x16x32_bf16(a3, b1, acc[3][1], 0,0,0);
    }
    float bv0 = bias[cb + row16], bv1 = bias[cb + 16 + row16];
    #pragma unroll
    for (int rt = 0; rt < 4; ++rt){
      #pragma unroll
      for (int i = 0; i < 4; ++i){
        int row = rbase + rt*16 + kg*4 + i;
        if (row < N_NODES){
          float v0 = acc[rt][0][i] + bv0;
          float v1 = acc[rt][1][i] + bv1;
          if (Of){
            Of[(size_t)row*128 + cb      + row16] = v0;
            Of[(size_t)row*128 + cb + 16 + row16] = v1;
          } else {
            Ob[(size_t)row*128 + cb      + row16] = (ushort)f2bf(v0);
            Ob[(size_t)row*128 + cb + 16 + row16] = (ushort)f2bf(v1);
          }
        }
      }
    }
  };
  gemm(Wtq, bq, q,  nullptr);
  gemm(Wtk, bk, nullptr, kb);
  gemm(Wtv, bv, nullptr, vb);
  gemm(Wts, bs, xr, nullptr);
}

// ---------------- edge attention aggregation (one wave per dst node), += into xr ----------------
__global__ __launch_bounds__(256) void k_agg(
  const float* __restrict__ q, const ushort* __restrict__ kbf, const ushort* __restrict__ vbf,
  const float* __restrict__ edge_attr, const float* __restrict__ We, const float* __restrict__ be,
  const int* __restrict__ srcIdx, const int* __restrict__ off, const int* __restrict__ bucket,
  float* __restrict__ xr)
{
  int tid = threadIdx.x;
  int node = blockIdx.x*4 + (tid >> 6);
  int lane = tid & 63;
  int d0 = lane*2;

  // per-lane We columns in registers
  float2 w[16];
  #pragma unroll
  for (int c = 0; c < 16; ++c) w[c] = *(const float2*)&We[c*128 + d0];
  float be0 = be[d0], be1 = be[d0+1];

  float2 qv = *(const float2*)&q[(size_t)node*128 + d0];
  int beg = __builtin_amdgcn_readfirstlane(off[node]);
  int end = __builtin_amdgcn_readfirstlane(off[node+1]);
  float m = -INFINITY, den = 0.f, a0 = 0.f, a1 = 0.f;

  int p = beg;
  for (; p + 4 <= end; p += 4){
    int ei0 = __builtin_amdgcn_readfirstlane(bucket[p+0]);
    int ei1 = __builtin_amdgcn_readfirstlane(bucket[p+1]);
    int ei2 = __builtin_amdgcn_readfirstlane(bucket[p+2]);
    int ei3 = __builtin_amdgcn_readfirstlane(bucket[p+3]);
    int s0 = __builtin_amdgcn_readfirstlane(srcIdx[ei0]);
    int s1 = __builtin_amdgcn_readfirstlane(srcIdx[ei1]);
    int s2 = __builtin_amdgcn_readfirstlane(srcIdx[ei2]);
    int s3 = __builtin_amdgcn_readfirstlane(srcIdx[ei3]);
    uint kw0 = *(const uint*)&kbf[(size_t)s0*128 + d0];
    uint kw1 = *(const uint*)&kbf[(size_t)s1*128 + d0];
    uint kw2 = *(const uint*)&kbf[(size_t)s2*128 + d0];
    uint kw3 = *(const uint*)&kbf[(size_t)s3*128 + d0];
    uint vw0 = *(const uint*)&vbf[(size_t)s0*128 + d0];
    uint vw1 = *(const uint*)&vbf[(size_t)s1*128 + d0];
    uint vw2 = *(const uint*)&vbf[(size_t)s2*128 + d0];
    uint vw3 = *(const uint*)&vbf[(size_t)s3*128 + d0];
    const float* ea0 = edge_attr + (size_t)ei0*16;
    const float* ea1 = edge_attr + (size_t)ei1*16;
    const float* ea2 = edge_attr + (size_t)ei2*16;
    const float* ea3 = edge_attr + (size_t)ei3*16;
    float4 a0a = *(const float4*)(ea0+0), a0b = *(const float4*)(ea0+4),
           a0c = *(const float4*)(ea0+8), a0d = *(const float4*)(ea0+12);
    float4 a1a = *(const float4*)(ea1+0), a1b = *(const float4*)(ea1+4),
           a1c = *(const float4*)(ea1+8), a1d = *(const float4*)(ea1+12);
    float4 a2a = *(const float4*)(ea2+0), a2b = *(const float4*)(ea2+4),
           a2c = *(const float4*)(ea2+8), a2d = *(const float4*)(ea2+12);
    float4 a3a = *(const float4*)(ea3+0), a3b = *(const float4*)(ea3+4),
           a3c = *(const float4*)(ea3+8), a3d = *(const float4*)(ea3+12);
    float av0[16] = {a0a.x,a0a.y,a0a.z,a0a.w, a0b.x,a0b.y,a0b.z,a0b.w,
                     a0c.x,a0c.y,a0c.z,a0c.w, a0d.x,a0d.y,a0d.z,a0d.w};
    float av1[16] = {a1a.x,a1a.y,a1a.z,a1a.w, a1b.x,a1b.y,a1b.z,a1b.w,
                     a1c.x,a1c.y,a1c.z,a1c.w, a1d.x,a1d.y,a1d.z,a1d.w};
    float av2[16] = {a2a.x,a2a.y,a2a.z,a2a.w, a2b.x,a2b.y,a2b.z,a2b.w,
                     a2c.x,a2c.y,a2c.z,a2c.w, a2d.x,a2d.y,a2d.z,a2d.w};
    float av3[16] = {a3a.x,a3a.y,a3a.z,a3a.w, a3b.x,a3b.y,a3b.z,a3b.w,
                     a3c.x,a3c.y,a3c.z,a3c.w, a3d.x,a3d.y,a3d.z,a3d.w};
    float ex0=be0, ey0=be1, ex1=be0, ey1=be1, ex2=be0, ey2=be1, ex3=be0, ey3=be1;
    #pragma unroll
    for (int c = 0; c < 16; ++c){
      ex0 += av0[c]*w[c].x; ey0 += av0[c]*w[c].y;
      ex1 += av1[c]*w[c].x; ey1 += av1[c]*w[c].y;
      ex2 += av2[c]*w[c].x; ey2 += av2[c]*w[c].y;
      ex3 += av3[c]*w[c].x; ey3 += av3[c]*w[c].y;
    }
    float kx0 = __uint_as_float(kw0 << 16), ky0 = __uint_as_float(kw0 & 0xffff0000u);
    float kx1 = __uint_as_float(kw1 << 16), ky1 = __uint_as_float(kw1 & 0xffff0000u);
    float kx2 = __uint_as_float(kw2 << 16), ky2 = __uint_as_float(kw2 & 0xffff0000u);
    float kx3 = __uint_as_float(kw3 << 16), ky3 = __uint_as_float(kw3 & 0xffff0000u);
    float p0 = qv.x*(kx0+ex0) + qv.y*(ky0+ey0);
    float p1 = qv.x*(kx1+ex1) + qv.y*(ky1+ey1);
    float p2 = qv.x*(kx2+ex2) + qv.y*(ky2+ey2);
    float p3 = qv.x*(kx3+ex3) + qv.y*(ky3+ey3);
    p0 += __shfl_xor(p0,1,64); p0 += __shfl_xor(p0,2,64); p0 += __shfl_xor(p0,4,64);
    p1 += __shfl_xor(p1,1,64); p1 += __shfl_xor(p1,2,64); p1 += __shfl_xor(p1,4,64);
    p2 += __shfl_xor(p2,1,64); p2 += __shfl_xor(p2,2,64); p2 += __shfl_xor(p2,4,64);
    p3 += __shfl_xor(p3,1,64); p3 += __shfl_xor(p3,2,64); p3 += __shfl_xor(p3,4,64);
    float sc0 = p0*0.25f, sc1 = p1*0.25f, sc2 = p2*0.25f, sc3 = p3*0.25f;
    float mn = fmaxf(fmaxf(m, fmaxf(sc0,sc1)), fmaxf(sc2,sc3));
    float corr = __expf(m - mn);
    float q0 = __expf(sc0 - mn), q1e = __expf(sc1 - mn);
    float q2e = __expf(sc2 - mn), q3e = __expf(sc3 - mn);
    den = den*corr + ((q0+q1e)+(q2e+q3e));
    float vx0 = __uint_as_float(vw0 << 16), vy0 = __uint_as_float(vw0 & 0xffff0000u);
    float vx1 = __uint_as_float(vw1 << 16), vy1 = __uint_as_float(vw1 & 0xffff0000u);
    float vx2 = __uint_as_float(vw2 << 16), vy2 = __uint_as_float(vw2 & 0xffff0000u);
    float vx3 = __uint_as_float(vw3 << 16), vy3 = __uint_as_float(vw3 & 0xffff0000u);
    a0 = a0*corr + q0*(vx0+ex0) + q1e*(vx1+ex1) + q2e*(vx2+ex2) + q3e*(vx3+ex3);
    a1 = a1*corr + q0*(vy0+ey0) + q1e*(vy1+ey1) + q2e*(vy2+ey2) + q3e*(vy3+ey3);
    m = mn;
  }
  for (; p < end; ++p){
    int ei = __builtin_amdgcn_readfirstlane(bucket[p]);
    int s  = __builtin_amdgcn_readfirstlane(srcIdx[ei]);
    uint kw = *(const uint*)&kbf[(size_t)s*128 + d0];
    uint vw = *(const uint*)&vbf[(size_t)s*128 + d0];
    const float* ea = edge_attr + (size_t)ei*16;
    float4 aa = *(const float4*)(ea+0), ab = *(const float4*)(ea+4),
           ac = *(const float4*)(ea+8), ad = *(const float4*)(ea+12);
    float av[16] = {aa.x,aa.y,aa.z,aa.w, ab.x,ab.y,ab.z,ab.w,
                    ac.x,ac.y,ac.z,ac.w, ad.x,ad.y,ad.z,ad.w};
    float ex=be0, ey=be1;
    #pragma unroll
    for (int c = 0; c < 16; ++c){ ex += av[c]*w[c].x; ey += av[c]*w[c].y; }
    float kx = __uint_as_float(kw << 16), ky = __uint_as_float(kw & 0xffff0000u);
    float pp = qv.x*(kx+ex) + qv.y*(ky+ey);
    pp += __shfl_xor(pp,1,64); pp += __shfl_xor(pp,2,64); pp += __shfl_xor(pp,4,64);
    float sc = pp*0.25f;
    float mn = fmaxf(m, sc);
    float corr = __expf(m - mn);
    float pe = __expf(sc - mn);
    den = den*corr + pe;
    float vx = __uint_as_float(vw << 16), vy = __uint_as_float(vw & 0xffff0000u);
    a0 = a0*corr + pe*(vx+ex);
    a1 = a1*corr + pe*(vy+ey);
    m = mn;
  }
  float2 xv = *(const float2*)&xr[(size_t)node*128 + d0];
  if (end > beg){ float inv = 1.0f/den; xv.x += a0*inv; xv.y += a1*inv; }
  *(float2*)&xr[(size_t)node*128 + d0] = xv;
}

// ---------------- post: res = aggout@Wp + bp + x ; A2 = bf16(LN(res)) ----------------
__global__ __launch_bounds__(256) void k_post(
  const float* __restrict__ aggout, const float* __restrict__ x,
  const short* __restrict__ Wtp, const float* __restrict__ bp,
  const float* __restrict__ lnw, const float* __restrict__ lnb,
  float* __restrict__ res, short* __restrict__ A2)
{
  __shared__ short A[64][136];
  __shared__ float rf[64][132];
  int tid = threadIdx.x;
  int rbase = blockIdx.x * 64;

  {
    int r = tid >> 2, j = tid & 3;
    int row = rbase + r;
    const float* p = aggout + (size_t)row*128 + j*32;
    #pragma unroll
    for (int i = 0; i < 8; ++i){
      float4 t = *(const float4*)(p + i*4);
      int c = j*32 + i*4;
      A[r][c+0] = f2bf(t.x); A[r][c+1] = f2bf(t.y);
      A[r][c+2] = f2bf(t.z); A[r][c+3] = f2bf(t.w);
    }
  }
  __syncthreads();

  int lane = tid & 63, wave = tid >> 6;
  int row16 = lane & 15, kg = lane >> 4;
  int cb = wave * 32;

  f32x4 acc[4][2] = {};
  #pragma unroll
  for (int kk = 0; kk < 128; kk += 32){
    int k0 = kk + kg*8;
    bf16x8 a0 = *(const bf16x8*)&A[ 0 + row16][k0];
    bf16x8 a1 = *(const bf16x8*)&A[16 + row16][k0];
    bf16x8 a2 = *(const bf16x8*)&A[32 + row16][k0];
    bf16x8 a3 = *(const bf16x8*)&A[48 + row16][k0];
    bf16x8 b0 = *(const bf16x8*)&Wtp[(size_t)(cb +      row16)*128 + k0];
    bf16x8 b1 = *(const bf16x8*)&Wtp[(size_t)(cb + 16 + row16)*128 + k0];
    acc[0][0] = __builtin_amdgcn_mfma_f32_16x16x32_bf16(a0, b0, acc[0][0], 0,0,0);
    acc[1][0] = __builtin_amdgcn_mfma_f32_16x16x32_bf16(a1, b0, acc[1][0], 0,0,0);
    acc[2][0] = __builtin_amdgcn_mfma_f32_16x16x32_bf16(a2, b0, acc[2][0], 0,0,0);
    acc[3][0] = __builtin_amdgcn_mfma_f32_16x16x32_bf16(a3, b0, acc[3][0], 0,0,0);
    acc[0][1] = __builtin_amdgcn_mfma_f32_16x16x32_bf16(a0, b1, acc[0][1], 0,0,0);
    acc[1][1] = __builtin_amdgcn_mfma_f32_16x16x32_bf16(a1, b1, acc[1][1], 0,0,0);
    acc[2][1] = __builtin_amdgcn_mfma_f32_16x16x32_bf16(a2, b1, acc[2][1], 0,0,0);
    acc[3][1] = __builtin_amdgcn_mfma_f32_16x16x32_bf16(a3, b1, acc[3][1], 0,0,0);
  }
  float bv0 = bp[cb + row16], bv1 = bp[cb + 16 + row16];
  #pragma unroll
  for (int rt = 0; rt < 4; ++rt){
    #pragma unroll
    for (int i = 0; i < 4; ++i){
      int rl = rt*16 + kg*4 + i;
      int row = rbase + rl;
      float v0 = acc[rt][0][i] + bv0;
      float v1 = acc[rt][1][i] + bv1;
      if (row < N_NODES){
        v0 += x[(size_t)row*128 + cb      + row16];
        v1 += x[(size_t)row*128 + cb + 16 + row16];
        res[(size_t)row*128 + cb      + row16] = v0;
        res[(size_t)row*128 + cb + 16 + row16] = v1;
      }
      rf[rl][cb      + row16] = v0;
      rf[rl][cb + 16 + row16] = v1;
    }
  }
  __syncthreads();

  {
    int r = tid >> 2, j = tid & 3;
    int row = rbase + r;
    float vals[32];
    #pragma unroll
    for (int i = 0; i < 8; ++i){
      float4 t = *(const float4*)&rf[r][j*32 + i*4];
      vals[i*4+0]=t.x; vals[i*4+1]=t.y; vals[i*4+2]=t.z; vals[i*4+3]=t.w;
    }
    float s = 0.f, s2 = 0.f;
    #pragma unroll
    for (int i = 0; i < 32; ++i){ s += vals[i]; s2 += vals[i]*vals[i]; }
    s  += __shfl_xor(s, 1, 64);  s  += __shfl_xor(s, 2, 64);
    s2 += __shfl_xor(s2, 1, 64); s2 += __shfl_xor(s2, 2, 64);
    float mean = s * 0.0078125f;
    float var  = s2 * 0.0078125f - mean*mean;
    float rstd = rsqrtf(var + 1e-5f);
    #pragma unroll
    for (int i = 0; i < 32; ++i){
      int col = j*32 + i;
      float xn = (vals[i]-mean)*rstd*lnw[col] + lnb[col];
      A2[(size_t)row*128 + col] = f2bf(xn);
    }
  }
}

// ---------------- mlp1: hid = bf16(gelu(A2 @ W1 + b1)) ----------------
__global__ __launch_bounds__(256) void k_mlp1(
  const short* __restrict__ A2, const short* __restrict__ W1t, const float* __restrict__ b1,
  short* __restrict__ hid)
{
  __shared__ short A[64][136];
  int tid = threadIdx.x;
  int rbase = blockIdx.x * 64;
  int ch = blockIdx.y;
  for (int idx = tid; idx < 1024; idx += 256){
    int r = idx >> 4, g = idx & 15;
    *(uint4*)&A[r][g*8] = *(const uint4*)&A2[((size_t)(rbase + r))*128 + g*8];
  }
  __syncthreads();

  int lane = tid & 63, wave = tid >> 6;
  int row16 = lane & 15, kg = lane >> 4;
  int cb = ch*256 + wave*64;

  f32x4 acc[4][4] = {};
  #pragma unroll
  for (int kk = 0; kk < 128; kk += 32){
    int k0 = kk + kg*8;
    bf16x8 a[4], b[4];
    #pragma unroll
    for (int rt = 0; rt < 4; ++rt) a[rt] = *(const bf16x8*)&A[rt*16 + row16][k0];
    #pragma unroll
    for (int ct = 0; ct < 4; ++ct) b[ct] = *(const bf16x8*)&W1t[(size_t)(cb + ct*16 + row16)*128 + k0];
    #pragma unroll
    for (int rt = 0; rt < 4; ++rt)
      #pragma unroll
      for (int ct = 0; ct < 4; ++ct)
        acc[rt][ct] = __builtin_amdgcn_mfma_f32_16x16x32_bf16(a[rt], b[ct], acc[rt][ct], 0,0,0);
  }
  float bv[4];
  #pragma unroll
  for (int ct = 0; ct < 4; ++ct) bv[ct] = b1[cb + ct*16 + row16];
  #pragma unroll
  for (int rt = 0; rt < 4; ++rt){
    #pragma unroll
    for (int ct = 0; ct < 4; ++ct){
      #pragma unroll
      for (int i = 0; i < 4; ++i){
        int row = rbase + rt*16 + kg*4 + i;
        hid[(size_t)row*512 + cb + ct*16 + row16] = f2bf(gelu_f(acc[rt][ct][i] + bv[ct]));
      }
    }
  }
}

// ---------------- mlp2: out = hid @ W2 + b2 + res ----------------
__global__ __launch_bounds__(256) void k_mlp2(
  const short* __restrict__ hid, const short* __restrict__ W2t, const float* __restrict__ b2,
  const float* __restrict__ res, float* __restrict__ out)
{
  __shared__ short A[64][136];
  int tid = threadIdx.x;
  int rbase = blockIdx.x * 64;
  int lane = tid & 63, wave = tid >> 6;
  int row16 = lane & 15, kg = lane >> 4;
  int cb = wave * 32;

  f32x4 acc[4][2] = {};
  for (int kc = 0; kc < 4; ++kc){
    __syncthreads();
    for (int idx = tid; idx < 1024; idx += 256){
      int r = idx >> 4, g = idx & 15;
      *(uint4*)&A[r][g*8] = *(const uint4*)&hid[((size_t)(rbase + r))*512 + kc*128 + g*8];
    }
    __syncthreads();
    #pragma unroll
    for (int kk = 0; kk < 128; kk += 32){
      int k0 = kk + kg*8;
      bf16x8 a0 = *(const bf16x8*)&A[ 0 + row16][k0];
      bf16x8 a1 = *(const bf16x8*)&A[16 + row16][k0];
      bf16x8 a2 = *(const bf16x8*)&A[32 + row16][k0];
      bf16x8 a3 = *(const bf16x8*)&A[48 + row16][k0];
      bf16x8 b0 = *(const bf16x8*)&W2t[(size_t)(cb +      row16)*512 + kc*128 + k0];
      bf16x8 b1 = *(const bf16x8*)&W2t[(size_t)(cb + 16 + row16)*512 + kc*128 + k0];
      acc[0][0] = __builtin_amdgcn_mfma_f32_16x16x32_bf16(a0, b0, acc[0][0], 0,0,0);
      acc[1][0] = __builtin_amdgcn_mfma_f32_16x16x32_bf16(a1, b0, acc[1][0], 0,0,0);
      acc[2][0] = __builtin_amdgcn_mfma_f32_16x16x32_bf16(a2, b0, acc[2][0], 0,0,0);
      acc[3][0] = __builtin_amdgcn_mfma_f32_16x16x32_bf16(a3, b0, acc[3][0], 0,0,0);
      acc[0][1] = __builtin_amdgcn_mfma_f32_16x16x32_bf16(a0, b1, acc[0][1], 0,0,0);
      acc[1][1] = __builtin_amdgcn_mfma_f32_16x16x32_bf16(a1, b1, acc[1][1], 0,0,0);
      acc[2][1] = __builtin_amdgcn_mfma_f32_16x16x32_bf16(a2, b1, acc[2][1], 0,0,0);
      acc[3][1] = __builtin_amdgcn_mfma_f32_16x16x32_bf16(a3, b1, acc[3][1], 0,0,0);
    }
  }
  float bv0 = b2[cb + row16], bv1 = b2[cb + 16 + row16];
  #pragma unroll
  for (int rt = 0; rt < 4; ++rt){
    #pragma unroll
    for (int i = 0; i < 4; ++i){
      int row = rbase + rt*16 + kg*4 + i;
      if (row < N_NODES){
        out[(size_t)row*128 + cb      + row16] = acc[rt][0][i] + bv0 + res[(size_t)row*128 + cb      + row16];
        out[(size_t)row*128 + cb + 16 + row16] = acc[rt][1][i] + bv1 + res[(size_t)row*128 + cb + 16 + row16];
      }
    }
  }
}

extern "C" void kernel_launch(void* const* d_in, const int* in_sizes, int n_in,
                              void* d_out, int out_size, void* d_ws, size_t ws_size,
                              hipStream_t stream)
{
  const float* x        = (const float*)d_in[0];
  const float* edge_attr= (const float*)d_in[1];
  const int*   edge_index=(const int*)d_in[2];
  const float* Wq = (const float*)d_in[3];  const float* bq = (const float*)d_in[4];
  const float* Wk = (const float*)d_in[5];  const float* bk = (const float*)d_in[6];
  const float* Wv = (const float*)d_in[7];  const float* bv = (const float*)d_in[8];
  const float* Wss= (const float*)d_in[9];  const float* bss= (const float*)d_in[10];
  const float* We = (const float*)d_in[11]; const float* be = (const float*)d_in[12];
  const float* Wp = (const float*)d_in[13]; const float* bp = (const float*)d_in[14];
  const float* lnaw=(const float*)d_in[15]; const float* lnab=(const float*)d_in[16];
  const float* lnmw=(const float*)d_in[17]; const float* lnmb=(const float*)d_in[18];
  const float* W1 = (const float*)d_in[19]; const float* b1 = (const float*)d_in[20];
  const float* W2 = (const float*)d_in[21]; const float* b2 = (const float*)d_in[22];

  float* ws = (float*)d_ws;
  // N_PAD = 50048 rows
  const size_t NP128 = 6406144;  // f32 [NP][128]
  const size_t NPH   = 3203072;  // bf16 [NP][128] in float-units
  float*  q    = ws;                         // f32; reused as res
  ushort* kbf  = (ushort*)(ws + NP128);      // bf16 [NP][128]; reused as A2
  ushort* vbf  = (ushort*)(ws + NP128 + NPH);// bf16 [NP][128]; start of hid region
  float*  xr   = ws + NP128 + 2*NPH;         // f32 [NP][128]
  // hid (bf16 [NP][512] = 12812288 float-units) spans vbf..22421504 (incl. dead xr)
  short* wts  = (short*)(ws + 22421504);
  short* Wtq  = wts;
  short* Wtk  = wts + 16384;
  short* Wtv  = wts + 32768;
  short* Wts_ = wts + 49152;
  short* Wtp  = wts + 65536;
  short* W1t  = wts + 81920;                 // [512][128] = 65536 shorts
  short* W2t  = wts + 147456;                // [128][512] = 65536 shorts
  // weights total 212992 shorts = 106496 FLOATS — iw must start after that
  int*   iw   = (int*)(ws + 22421504 + 106496);
  int* deg    = iw;
  int* off    = iw + 50000;
  int* cursor = iw + 100001;
  int* bucket = iw + 150001;

  float* res  = q;
  short* A2   = (short*)kbf;
  short* hid  = (short*)vbf;

  const int* srcIdx = edge_index;
  const int* dstIdx = edge_index + N_EDGES;

  // weight prep
  k_tconv<<<64,  256, 0, stream>>>(Wq,  Wtq, 128, 128);
  k_tconv<<<64,  256, 0, stream>>>(Wk,  Wtk, 128, 128);
  k_tconv<<<64,  256, 0, stream>>>(Wv,  Wtv, 128, 128);
  k_tconv<<<64,  256, 0, stream>>>(Wss, Wts_,128, 128);
  k_tconv<<<64,  256, 0, stream>>>(Wp,  Wtp, 128, 128);
  k_tconv<<<256, 256, 0, stream>>>(W1,  W1t, 128, 512);
  k_tconv<<<256, 256, 0, stream>>>(W2,  W2t, 512, 128);

  // CSR
  hipMemsetAsync(deg, 0, N_NODES*sizeof(int), stream);
  k_deg<<<(N_EDGES+255)/256, 256, 0, stream>>>(dstIdx, deg);
  k_scan<<<1, 1024, 0, stream>>>(deg, off, cursor);
  k_scatter<<<(N_EDGES+255)/256, 256, 0, stream>>>(dstIdx, cursor, bucket);

  // main pipeline
  k_nodeproj<<<782, 256, 0, stream>>>(x, lnaw, lnab, Wtq, Wtk, Wtv, Wts_,
                                      bq, bk, bv, bss, q, kbf, vbf, xr);
  k_agg<<<N_NODES/4, 256, 0, stream>>>(q, kbf, vbf, edge_attr, We, be,
                                       srcIdx, off, bucket, xr);
  k_post<<<782, 256, 0, stream>>>(xr, x, Wtp, bp, lnmw, lnmb, res, A2);
  k_mlp1<<<dim3(782,2), 256, 0, stream>>>(A2, W1t, b1, hid);
  k_mlp2<<<782, 256, 0, stream>>>(hid, W2t, b2, res, (float*)d_out);

  hipMemcpyAsync((float*)d_out + (size_t)N_NODES*128, edge_attr,
                 (size_t)N_EDGES*16*sizeof(float), hipMemcpyDeviceToDevice, stream);
}

// Round 5
// 419.512 us; speedup vs baseline: 3.0462x; 1.0176x over previous
//
#include <hip/hip_runtime.h>
#include <math.h>

#define N_NODES 50000
#define N_EDGES 800000

typedef __attribute__((ext_vector_type(8))) short bf16x8;
typedef __attribute__((ext_vector_type(4))) float f32x4;

__device__ __forceinline__ short f2bf(float f){
  unsigned u = __float_as_uint(f);
  unsigned r = (u + 0x7FFFu + ((u >> 16) & 1u)) >> 16;
  return (short)r;
}

__device__ __forceinline__ float gelu_f(float x){
  float z = 0.7978845608028654f*(x + 0.044715f*x*x*x);
  float e = __expf(2.0f*z);
  return 0.5f*x*(2.0f - 2.0f/(e + 1.0f));   // 0.5x(1+tanh z), inf-safe
}

// ---------------- weight transpose + bf16 convert: Wt[n][k] = bf16(W[k][n]) ----------------
__global__ __launch_bounds__(256) void k_tconv(const float* __restrict__ W, short* __restrict__ Wt,
                                               int K, int Nn){
  int i = blockIdx.x*256 + threadIdx.x;
  if (i < K*Nn){
    int n = i / K, k = i - n*K;
    Wt[(size_t)n*K + k] = f2bf(W[(size_t)k*Nn + n]);
  }
}

struct TC6 { const float* src[6]; short* dst[6]; };
__global__ __launch_bounds__(256) void k_tconv6(TC6 t){
  int b = blockIdx.y;
  const float* W = t.src[b];
  short* Wt = t.dst[b];
  int i = blockIdx.x*256 + threadIdx.x;   // 64 blocks x 256 = 16384
  int n = i >> 7, k = i & 127;
  Wt[n*128 + k] = f2bf(W[k*128 + n]);
}

// ---------------- Wqm = Wq @ M, bqm = bq @ M  (M[d][h*16+c] = We[c,d] for d in head h) ----------------
__global__ __launch_bounds__(256) void k_wqm(const float* __restrict__ Wq, const float* __restrict__ We,
                                             const float* __restrict__ bq,
                                             float* __restrict__ Wqm, float* __restrict__ bqm){
  int i = blockIdx.x*256 + threadIdx.x;
  if (i < 16384){
    int k = i >> 7, j = i & 127;
    int h = j >> 4, c = j & 15;
    float s = 0.f;
    #pragma unroll
    for (int dd = 0; dd < 16; ++dd)
      s += Wq[k*128 + h*16 + dd] * We[c*128 + h*16 + dd];
    Wqm[i] = s;
    if (k == 0){
      float t = 0.f;
      #pragma unroll
      for (int dd = 0; dd < 16; ++dd)
        t += bq[h*16 + dd] * We[c*128 + h*16 + dd];
      bqm[j] = t;
    }
  }
}

// ---------------- CSR build ----------------
__global__ __launch_bounds__(256) void k_deg(const int* __restrict__ dst, int* __restrict__ deg){
  int i = blockIdx.x*256 + threadIdx.x;
  if (i < N_EDGES) atomicAdd(&deg[dst[i]], 1);
}

__global__ __launch_bounds__(1024) void k_scan(const int* __restrict__ deg,
                                               int* __restrict__ off, int* __restrict__ cursor){
  __shared__ int wsum[16];
  __shared__ int chunk_total;
  __shared__ int carry;
  int tid = threadIdx.x, lane = tid & 63, wid = tid >> 6;
  if (tid == 0) carry = 0;
  __syncthreads();
  for (int base = 0; base < N_NODES; base += 1024){
    int i = base + tid;
    int val = (i < N_NODES) ? deg[i] : 0;
    int incl = val;
    #pragma unroll
    for (int s = 1; s < 64; s <<= 1){
      int t = __shfl_up(incl, s, 64);
      if (lane >= s) incl += t;
    }
    if (lane == 63) wsum[wid] = incl;
    __syncthreads();
    if (tid < 16){
      int t = wsum[tid];
      int inc = t;
      #pragma unroll
      for (int s = 1; s < 16; s <<= 1){
        int u = __shfl_up(inc, s, 64);
        if (tid >= s) inc += u;
      }
      wsum[tid] = inc - t;
      if (tid == 15) chunk_total = inc;
    }
    __syncthreads();
    int excl = carry + wsum[wid] + (incl - val);
    if (i < N_NODES){ off[i] = excl; cursor[i] = excl; }
    __syncthreads();
    if (tid == 0) carry += chunk_total;
    __syncthreads();
  }
  if (threadIdx.x == 0) off[N_NODES] = carry;
}

__global__ __launch_bounds__(256) void k_scatter(const int* __restrict__ dst,
                                                 int* __restrict__ cursor, int* __restrict__ bucket){
  int i = blockIdx.x*256 + threadIdx.x;
  if (i < N_EDGES){
    int d = dst[i];
    int pos = atomicAdd(&cursor[d], 1);
    bucket[pos] = i;
  }
}

// ---------------- node projections: LN(x) -> q, qWe, k(bf16), v(bf16), x_r ----------------
__global__ __launch_bounds__(256) void k_nodeproj(
  const float* __restrict__ x, const float* __restrict__ lnw, const float* __restrict__ lnb,
  const short* __restrict__ Wtq, const short* __restrict__ Wtqm,
  const short* __restrict__ Wtk, const short* __restrict__ Wtv, const short* __restrict__ Wts,
  const float* __restrict__ bq, const float* __restrict__ bqm,
  const float* __restrict__ bk, const float* __restrict__ bv, const float* __restrict__ bs,
  float* __restrict__ q, float* __restrict__ qwe,
  ushort* __restrict__ kb, ushort* __restrict__ vb, float* __restrict__ xr)
{
  __shared__ short A[64][136];
  int tid = threadIdx.x;
  int rbase = blockIdx.x * 64;

  // LN phase: 4 threads per row, 32 cols each
  {
    int r = tid >> 2, j = tid & 3;
    int row = rbase + r;
    bool ok = row < N_NODES;
    const float* xp = x + (size_t)row*128 + j*32;
    float vals[32];
    #pragma unroll
    for (int i = 0; i < 8; ++i){
      float4 t = ok ? *(const float4*)(xp + i*4) : make_float4(0,0,0,0);
      vals[i*4+0]=t.x; vals[i*4+1]=t.y; vals[i*4+2]=t.z; vals[i*4+3]=t.w;
    }
    float s = 0.f, s2 = 0.f;
    #pragma unroll
    for (int i = 0; i < 32; ++i){ s += vals[i]; s2 += vals[i]*vals[i]; }
    s  += __shfl_xor(s, 1, 64);  s  += __shfl_xor(s, 2, 64);
    s2 += __shfl_xor(s2, 1, 64); s2 += __shfl_xor(s2, 2, 64);
    float mean = s * 0.0078125f;
    float var  = s2 * 0.0078125f - mean*mean;
    float rstd = rsqrtf(var + 1e-5f);
    #pragma unroll
    for (int i = 0; i < 32; ++i){
      int col = j*32 + i;
      float xn = (vals[i]-mean)*rstd*lnw[col] + lnb[col];
      A[r][col] = f2bf(xn);
    }
  }
  __syncthreads();

  int lane = tid & 63, wave = tid >> 6;
  int row16 = lane & 15, kg = lane >> 4;
  int cb = wave * 32;

  auto gemm = [&](const short* __restrict__ B, const float* __restrict__ bias,
                  float* __restrict__ Of, ushort* __restrict__ Ob){
    f32x4 acc[4][2] = {};
    #pragma unroll
    for (int kk = 0; kk < 128; kk += 32){
      int k0 = kk + kg*8;
      bf16x8 a0 = *(const bf16x8*)&A[ 0 + row16][k0];
      bf16x8 a1 = *(const bf16x8*)&A[16 + row16][k0];
      bf16x8 a2 = *(const bf16x8*)&A[32 + row16][k0];
      bf16x8 a3 = *(const bf16x8*)&A[48 + row16][k0];
      bf16x8 b0 = *(const bf16x8*)&B[(size_t)(cb +      row16)*128 + k0];
      bf16x8 b1 = *(const bf16x8*)&B[(size_t)(cb + 16 + row16)*128 + k0];
      acc[0][0] = __builtin_amdgcn_mfma_f32_16x16x32_bf16(a0, b0, acc[0][0], 0,0,0);
      acc[1][0] = __builtin_amdgcn_mfma_f32_16x16x32_bf16(a1, b0, acc[1][0], 0,0,0);
      acc[2][0] = __builtin_amdgcn_mfma_f32_16x16x32_bf16(a2, b0, acc[2][0], 0,0,0);
      acc[3][0] = __builtin_amdgcn_mfma_f32_16x16x32_bf16(a3, b0, acc[3][0], 0,0,0);
      acc[0][1] = __builtin_amdgcn_mfma_f32_16x16x32_bf16(a0, b1, acc[0][1], 0,0,0);
      acc[1][1] = __builtin_amdgcn_mfma_f32_16x16x32_bf16(a1, b1, acc[1][1], 0,0,0);
      acc[2][1] = __builtin_amdgcn_mfma_f32_16x16x32_bf16(a2, b1, acc[2][1], 0,0,0);
      acc[3][1] = __builtin_amdgcn_mfma_f32_16x16x32_bf16(a3, b1, acc[3][1], 0,0,0);
    }
    float bv0 = bias[cb + row16], bv1 = bias[cb + 16 + row16];
    #pragma unroll
    for (int rt = 0; rt < 4; ++rt){
      #pragma unroll
      for (int i = 0; i < 4; ++i){
        int row = rbase + rt*16 + kg*4 + i;
        if (row < N_NODES){
          float v0 = acc[rt][0][i] + bv0;
          float v1 = acc[rt][1][i] + bv1;
          if (Of){
            Of[(size_t)row*128 + cb      + row16] = v0;
            Of[(size_t)row*128 + cb + 16 + row16] = v1;
          } else {
            Ob[(size_t)row*128 + cb      + row16] = (ushort)f2bf(v0);
            Ob[(size_t)row*128 + cb + 16 + row16] = (ushort)f2bf(v1);
          }
        }
      }
    }
  };
  gemm(Wtq,  bq,  q,   nullptr);
  gemm(Wtqm, bqm, qwe, nullptr);
  gemm(Wtk,  bk,  nullptr, kb);
  gemm(Wtv,  bv,  nullptr, vb);
  gemm(Wts,  bs,  xr,  nullptr);
}

// ---------------- edge attention aggregation (one wave per dst node), += into xr ----------------
// score = (q.k[src] + <ea, qWe_h>)/4   (q.be term dropped: softmax shift-invariant)
// out   = (sum pe*v + We^T (sum pe*ea))/den + be
__global__ __launch_bounds__(256) void k_agg(
  const float* __restrict__ q, const float* __restrict__ qwe,
  const ushort* __restrict__ kbf, const ushort* __restrict__ vbf,
  const float* __restrict__ edge_attr, const float* __restrict__ We, const float* __restrict__ be,
  const int* __restrict__ srcIdx, const int* __restrict__ off, const int* __restrict__ bucket,
  float* __restrict__ xr)
{
  int tid = threadIdx.x;
  int node = blockIdx.x*4 + (tid >> 6);
  int lane = tid & 63;
  int d0 = lane*2;
  int c0 = (lane & 7)*2;

  float2 qv = *(const float2*)&q[(size_t)node*128 + d0];
  float2 qe = *(const float2*)&qwe[(size_t)node*128 + (lane>>3)*16 + c0];
  int beg = __builtin_amdgcn_readfirstlane(off[node]);
  int end = __builtin_amdgcn_readfirstlane(off[node+1]);
  float m = -INFINITY, den = 0.f, a0 = 0.f, a1 = 0.f, S0 = 0.f, S1 = 0.f;

  int p = beg;
  for (; p + 4 <= end; p += 4){
    int ei0 = __builtin_amdgcn_readfirstlane(bucket[p+0]);
    int ei1 = __builtin_amdgcn_readfirstlane(bucket[p+1]);
    int ei2 = __builtin_amdgcn_readfirstlane(bucket[p+2]);
    int ei3 = __builtin_amdgcn_readfirstlane(bucket[p+3]);
    int s0 = __builtin_amdgcn_readfirstlane(srcIdx[ei0]);
    int s1 = __builtin_amdgcn_readfirstlane(srcIdx[ei1]);
    int s2 = __builtin_amdgcn_readfirstlane(srcIdx[ei2]);
    int s3 = __builtin_amdgcn_readfirstlane(srcIdx[ei3]);
    uint kw0 = *(const uint*)&kbf[(size_t)s0*128 + d0];
    uint kw1 = *(const uint*)&kbf[(size_t)s1*128 + d0];
    uint kw2 = *(const uint*)&kbf[(size_t)s2*128 + d0];
    uint kw3 = *(const uint*)&kbf[(size_t)s3*128 + d0];
    uint vw0 = *(const uint*)&vbf[(size_t)s0*128 + d0];
    uint vw1 = *(const uint*)&vbf[(size_t)s1*128 + d0];
    uint vw2 = *(const uint*)&vbf[(size_t)s2*128 + d0];
    uint vw3 = *(const uint*)&vbf[(size_t)s3*128 + d0];
    float2 e0 = *(const float2*)&edge_attr[(size_t)ei0*16 + c0];
    float2 e1 = *(const float2*)&edge_attr[(size_t)ei1*16 + c0];
    float2 e2 = *(const float2*)&edge_attr[(size_t)ei2*16 + c0];
    float2 e3 = *(const float2*)&edge_attr[(size_t)ei3*16 + c0];

    float kx0 = __uint_as_float(kw0 << 16), ky0 = __uint_as_float(kw0 & 0xffff0000u);
    float kx1 = __uint_as_float(kw1 << 16), ky1 = __uint_as_float(kw1 & 0xffff0000u);
    float kx2 = __uint_as_float(kw2 << 16), ky2 = __uint_as_float(kw2 & 0xffff0000u);
    float kx3 = __uint_as_float(kw3 << 16), ky3 = __uint_as_float(kw3 & 0xffff0000u);
    float p0 = qv.x*kx0 + qv.y*ky0 + qe.x*e0.x + qe.y*e0.y;
    float p1 = qv.x*kx1 + qv.y*ky1 + qe.x*e1.x + qe.y*e1.y;
    float p2 = qv.x*kx2 + qv.y*ky2 + qe.x*e2.x + qe.y*e2.y;
    float p3 = qv.x*kx3 + qv.y*ky3 + qe.x*e3.x + qe.y*e3.y;
    p0 += __shfl_xor(p0,1,64); p0 += __shfl_xor(p0,2,64); p0 += __shfl_xor(p0,4,64);
    p1 += __shfl_xor(p1,1,64); p1 += __shfl_xor(p1,2,64); p1 += __shfl_xor(p1,4,64);
    p2 += __shfl_xor(p2,1,64); p2 += __shfl_xor(p2,2,64); p2 += __shfl_xor(p2,4,64);
    p3 += __shfl_xor(p3,1,64); p3 += __shfl_xor(p3,2,64); p3 += __shfl_xor(p3,4,64);
    float sc0 = p0*0.25f, sc1 = p1*0.25f, sc2 = p2*0.25f, sc3 = p3*0.25f;
    float mn = fmaxf(fmaxf(m, fmaxf(sc0,sc1)), fmaxf(sc2,sc3));
    float corr = __expf(m - mn);
    float w0 = __expf(sc0 - mn), w1 = __expf(sc1 - mn);
    float w2 = __expf(sc2 - mn), w3 = __expf(sc3 - mn);
    den = den*corr + ((w0+w1)+(w2+w3));
    float vx0 = __uint_as_float(vw0 << 16), vy0 = __uint_as_float(vw0 & 0xffff0000u);
    float vx1 = __uint_as_float(vw1 << 16), vy1 = __uint_as_float(vw1 & 0xffff0000u);
    float vx2 = __uint_as_float(vw2 << 16), vy2 = __uint_as_float(vw2 & 0xffff0000u);
    float vx3 = __uint_as_float(vw3 << 16), vy3 = __uint_as_float(vw3 & 0xffff0000u);
    a0 = a0*corr + (w0*vx0 + w1*vx1) + (w2*vx2 + w3*vx3);
    a1 = a1*corr + (w0*vy0 + w1*vy1) + (w2*vy2 + w3*vy3);
    S0 = S0*corr + (w0*e0.x + w1*e1.x) + (w2*e2.x + w3*e3.x);
    S1 = S1*corr + (w0*e0.y + w1*e1.y) + (w2*e2.y + w3*e3.y);
    m = mn;
  }
  for (; p < end; ++p){
    int ei = __builtin_amdgcn_readfirstlane(bucket[p]);
    int s  = __builtin_amdgcn_readfirstlane(srcIdx[ei]);
    uint kw = *(const uint*)&kbf[(size_t)s*128 + d0];
    uint vw = *(const uint*)&vbf[(size_t)s*128 + d0];
    float2 ev = *(const float2*)&edge_attr[(size_t)ei*16 + c0];
    float kx = __uint_as_float(kw << 16), ky = __uint_as_float(kw & 0xffff0000u);
    float pp = qv.x*kx + qv.y*ky + qe.x*ev.x + qe.y*ev.y;
    pp += __shfl_xor(pp,1,64); pp += __shfl_xor(pp,2,64); pp += __shfl_xor(pp,4,64);
    float sc = pp*0.25f;
    float mn = fmaxf(m, sc);
    float corr = __expf(m - mn);
    float pe = __expf(sc - mn);
    den = den*corr + pe;
    float vx = __uint_as_float(vw << 16), vy = __uint_as_float(vw & 0xffff0000u);
    a0 = a0*corr + pe*vx;
    a1 = a1*corr + pe*vy;
    S0 = S0*corr + pe*ev.x;
    S1 = S1*corr + pe*ev.y;
    m = mn;
  }

  if (end > beg){
    float inv = 1.0f/den;
    float ox = a0, oy = a1;
    int gbase = lane & 56;
    #pragma unroll
    for (int j = 0; j < 8; ++j){
      float sj0 = __shfl(S0, gbase + j, 64);
      float sj1 = __shfl(S1, gbase + j, 64);
      float2 wA = *(const float2*)&We[(2*j  )*128 + d0];
      float2 wB = *(const float2*)&We[(2*j+1)*128 + d0];
      ox += sj0*wA.x + sj1*wB.x;
      oy += sj0*wA.y + sj1*wB.y;
    }
    float2 bev = *(const float2*)&be[d0];
    float2 xv = *(const float2*)&xr[(size_t)node*128 + d0];
    xv.x += ox*inv + bev.x;
    xv.y += oy*inv + bev.y;
    *(float2*)&xr[(size_t)node*128 + d0] = xv;
  }
}

// ---------------- post: res = aggout@Wp + bp + x ; A2 = bf16(LN(res)) ----------------
__global__ __launch_bounds__(256) void k_post(
  const float* __restrict__ aggout, const float* __restrict__ x,
  const short* __restrict__ Wtp, const float* __restrict__ bp,
  const float* __restrict__ lnw, const float* __restrict__ lnb,
  float* __restrict__ res, short* __restrict__ A2)
{
  __shared__ short A[64][136];
  __shared__ float rf[64][132];
  int tid = threadIdx.x;
  int rbase = blockIdx.x * 64;

  {
    int r = tid >> 2, j = tid & 3;
    int row = rbase + r;
    const float* p = aggout + (size_t)row*128 + j*32;
    #pragma unroll
    for (int i = 0; i < 8; ++i){
      float4 t = *(const float4*)(p + i*4);
      int c = j*32 + i*4;
      A[r][c+0] = f2bf(t.x); A[r][c+1] = f2bf(t.y);
      A[r][c+2] = f2bf(t.z); A[r][c+3] = f2bf(t.w);
    }
  }
  __syncthreads();

  int lane = tid & 63, wave = tid >> 6;
  int row16 = lane & 15, kg = lane >> 4;
  int cb = wave * 32;

  f32x4 acc[4][2] = {};
  #pragma unroll
  for (int kk = 0; kk < 128; kk += 32){
    int k0 = kk + kg*8;
    bf16x8 a0 = *(const bf16x8*)&A[ 0 + row16][k0];
    bf16x8 a1 = *(const bf16x8*)&A[16 + row16][k0];
    bf16x8 a2 = *(const bf16x8*)&A[32 + row16][k0];
    bf16x8 a3 = *(const bf16x8*)&A[48 + row16][k0];
    bf16x8 b0 = *(const bf16x8*)&Wtp[(size_t)(cb +      row16)*128 + k0];
    bf16x8 b1 = *(const bf16x8*)&Wtp[(size_t)(cb + 16 + row16)*128 + k0];
    acc[0][0] = __builtin_amdgcn_mfma_f32_16x16x32_bf16(a0, b0, acc[0][0], 0,0,0);
    acc[1][0] = __builtin_amdgcn_mfma_f32_16x16x32_bf16(a1, b0, acc[1][0], 0,0,0);
    acc[2][0] = __builtin_amdgcn_mfma_f32_16x16x32_bf16(a2, b0, acc[2][0], 0,0,0);
    acc[3][0] = __builtin_amdgcn_mfma_f32_16x16x32_bf16(a3, b0, acc[3][0], 0,0,0);
    acc[0][1] = __builtin_amdgcn_mfma_f32_16x16x32_bf16(a0, b1, acc[0][1], 0,0,0);
    acc[1][1] = __builtin_amdgcn_mfma_f32_16x16x32_bf16(a1, b1, acc[1][1], 0,0,0);
    acc[2][1] = __builtin_amdgcn_mfma_f32_16x16x32_bf16(a2, b1, acc[2][1], 0,0,0);
    acc[3][1] = __builtin_amdgcn_mfma_f32_16x16x32_bf16(a3, b1, acc[3][1], 0,0,0);
  }
  float bv0 = bp[cb + row16], bv1 = bp[cb + 16 + row16];
  #pragma unroll
  for (int rt = 0; rt < 4; ++rt){
    #pragma unroll
    for (int i = 0; i < 4; ++i){
      int rl = rt*16 + kg*4 + i;
      int row = rbase + rl;
      float v0 = acc[rt][0][i] + bv0;
      float v1 = acc[rt][1][i] + bv1;
      if (row < N_NODES){
        v0 += x[(size_t)row*128 + cb      + row16];
        v1 += x[(size_t)row*128 + cb + 16 + row16];
        res[(size_t)row*128 + cb      + row16] = v0;
        res[(size_t)row*128 + cb + 16 + row16] = v1;
      }
      rf[rl][cb      + row16] = v0;
      rf[rl][cb + 16 + row16] = v1;
    }
  }
  __syncthreads();

  {
    int r = tid >> 2, j = tid & 3;
    int row = rbase + r;
    float vals[32];
    #pragma unroll
    for (int i = 0; i < 8; ++i){
      float4 t = *(const float4*)&rf[r][j*32 + i*4];
      vals[i*4+0]=t.x; vals[i*4+1]=t.y; vals[i*4+2]=t.z; vals[i*4+3]=t.w;
    }
    float s = 0.f, s2 = 0.f;
    #pragma unroll
    for (int i = 0; i < 32; ++i){ s += vals[i]; s2 += vals[i]*vals[i]; }
    s  += __shfl_xor(s, 1, 64);  s  += __shfl_xor(s, 2, 64);
    s2 += __shfl_xor(s2, 1, 64); s2 += __shfl_xor(s2, 2, 64);
    float mean = s * 0.0078125f;
    float var  = s2 * 0.0078125f - mean*mean;
    float rstd = rsqrtf(var + 1e-5f);
    #pragma unroll
    for (int i = 0; i < 32; ++i){
      int col = j*32 + i;
      float xn = (vals[i]-mean)*rstd*lnw[col] + lnb[col];
      A2[(size_t)row*128 + col] = f2bf(xn);
    }
  }
}

// ---------------- mlp1: hid = bf16(gelu(A2 @ W1 + b1)) ----------------
__global__ __launch_bounds__(256) void k_mlp1(
  const short* __restrict__ A2, const short* __restrict__ W1t, const float* __restrict__ b1,
  short* __restrict__ hid)
{
  __shared__ short A[64][136];
  int tid = threadIdx.x;
  int rbase = blockIdx.x * 64;
  int ch = blockIdx.y;
  for (int idx = tid; idx < 1024; idx += 256){
    int r = idx >> 4, g = idx & 15;
    *(uint4*)&A[r][g*8] = *(const uint4*)&A2[((size_t)(rbase + r))*128 + g*8];
  }
  __syncthreads();

  int lane = tid & 63, wave = tid >> 6;
  int row16 = lane & 15, kg = lane >> 4;
  int cb = ch*256 + wave*64;

  f32x4 acc[4][4] = {};
  #pragma unroll
  for (int kk = 0; kk < 128; kk += 32){
    int k0 = kk + kg*8;
    bf16x8 a[4], b[4];
    #pragma unroll
    for (int rt = 0; rt < 4; ++rt) a[rt] = *(const bf16x8*)&A[rt*16 + row16][k0];
    #pragma unroll
    for (int ct = 0; ct < 4; ++ct) b[ct] = *(const bf16x8*)&W1t[(size_t)(cb + ct*16 + row16)*128 + k0];
    #pragma unroll
    for (int rt = 0; rt < 4; ++rt)
      #pragma unroll
      for (int ct = 0; ct < 4; ++ct)
        acc[rt][ct] = __builtin_amdgcn_mfma_f32_16x16x32_bf16(a[rt], b[ct], acc[rt][ct], 0,0,0);
  }
  float bv[4];
  #pragma unroll
  for (int ct = 0; ct < 4; ++ct) bv[ct] = b1[cb + ct*16 + row16];
  #pragma unroll
  for (int rt = 0; rt < 4; ++rt){
    #pragma unroll
    for (int ct = 0; ct < 4; ++ct){
      #pragma unroll
      for (int i = 0; i < 4; ++i){
        int row = rbase + rt*16 + kg*4 + i;
        hid[(size_t)row*512 + cb + ct*16 + row16] = f2bf(gelu_f(acc[rt][ct][i] + bv[ct]));
      }
    }
  }
}

// ---------------- mlp2: out = hid @ W2 + b2 + res ----------------
__global__ __launch_bounds__(256) void k_mlp2(
  const short* __restrict__ hid, const short* __restrict__ W2t, const float* __restrict__ b2,
  const float* __restrict__ res, float* __restrict__ out)
{
  __shared__ short A[64][136];
  int tid = threadIdx.x;
  int rbase = blockIdx.x * 64;
  int lane = tid & 63, wave = tid >> 6;
  int row16 = lane & 15, kg = lane >> 4;
  int cb = wave * 32;

  f32x4 acc[4][2] = {};
  for (int kc = 0; kc < 4; ++kc){
    __syncthreads();
    for (int idx = tid; idx < 1024; idx += 256){
      int r = idx >> 4, g = idx & 15;
      *(uint4*)&A[r][g*8] = *(const uint4*)&hid[((size_t)(rbase + r))*512 + kc*128 + g*8];
    }
    __syncthreads();
    #pragma unroll
    for (int kk = 0; kk < 128; kk += 32){
      int k0 = kk + kg*8;
      bf16x8 a0 = *(const bf16x8*)&A[ 0 + row16][k0];
      bf16x8 a1 = *(const bf16x8*)&A[16 + row16][k0];
      bf16x8 a2 = *(const bf16x8*)&A[32 + row16][k0];
      bf16x8 a3 = *(const bf16x8*)&A[48 + row16][k0];
      bf16x8 b0 = *(const bf16x8*)&W2t[(size_t)(cb +      row16)*512 + kc*128 + k0];
      bf16x8 b1 = *(const bf16x8*)&W2t[(size_t)(cb + 16 + row16)*512 + kc*128 + k0];
      acc[0][0] = __builtin_amdgcn_mfma_f32_16x16x32_bf16(a0, b0, acc[0][0], 0,0,0);
      acc[1][0] = __builtin_amdgcn_mfma_f32_16x16x32_bf16(a1, b0, acc[1][0], 0,0,0);
      acc[2][0] = __builtin_amdgcn_mfma_f32_16x16x32_bf16(a2, b0, acc[2][0], 0,0,0);
      acc[3][0] = __builtin_amdgcn_mfma_f32_16x16x32_bf16(a3, b0, acc[3][0], 0,0,0);
      acc[0][1] = __builtin_amdgcn_mfma_f32_16x16x32_bf16(a0, b1, acc[0][1], 0,0,0);
      acc[1][1] = __builtin_amdgcn_mfma_f32_16x16x32_bf16(a1, b1, acc[1][1], 0,0,0);
      acc[2][1] = __builtin_amdgcn_mfma_f32_16x16x32_bf16(a2, b1, acc[2][1], 0,0,0);
      acc[3][1] = __builtin_amdgcn_mfma_f32_16x16x32_bf16(a3, b1, acc[3][1], 0,0,0);
    }
  }
  float bv0 = b2[cb + row16], bv1 = b2[cb + 16 + row16];
  #pragma unroll
  for (int rt = 0; rt < 4; ++rt){
    #pragma unroll
    for (int i = 0; i < 4; ++i){
      int row = rbase + rt*16 + kg*4 + i;
      if (row < N_NODES){
        out[(size_t)row*128 + cb      + row16] = acc[rt][0][i] + bv0 + res[(size_t)row*128 + cb      + row16];
        out[(size_t)row*128 + cb + 16 + row16] = acc[rt][1][i] + bv1 + res[(size_t)row*128 + cb + 16 + row16];
      }
    }
  }
}

extern "C" void kernel_launch(void* const* d_in, const int* in_sizes, int n_in,
                              void* d_out, int out_size, void* d_ws, size_t ws_size,
                              hipStream_t stream)
{
  const float* x        = (const float*)d_in[0];
  const float* edge_attr= (const float*)d_in[1];
  const int*   edge_index=(const int*)d_in[2];
  const float* Wq = (const float*)d_in[3];  const float* bq = (const float*)d_in[4];
  const float* Wk = (const float*)d_in[5];  const float* bk = (const float*)d_in[6];
  const float* Wv = (const float*)d_in[7];  const float* bv = (const float*)d_in[8];
  const float* Wss= (const float*)d_in[9];  const float* bss= (const float*)d_in[10];
  const float* We = (const float*)d_in[11]; const float* be = (const float*)d_in[12];
  const float* Wp = (const float*)d_in[13]; const float* bp = (const float*)d_in[14];
  const float* lnaw=(const float*)d_in[15]; const float* lnab=(const float*)d_in[16];
  const float* lnmw=(const float*)d_in[17]; const float* lnmb=(const float*)d_in[18];
  const float* W1 = (const float*)d_in[19]; const float* b1 = (const float*)d_in[20];
  const float* W2 = (const float*)d_in[21]; const float* b2 = (const float*)d_in[22];

  float* ws = (float*)d_ws;
  // N_PAD = 50048 rows
  const size_t NP128 = 6406144;  // f32 [NP][128]
  const size_t NPH   = 3203072;  // bf16 [NP][128] in float-units
  float*  q    = ws;                           // f32; reused as res
  ushort* kbf  = (ushort*)(ws + NP128);        // bf16 [NP][128]; reused as A2
  ushort* vbf  = (ushort*)(ws + NP128 + NPH);  // bf16 [NP][128]; start of hid region
  float*  xr   = ws + 12812288;                // f32 [NP][128]
  float*  qwe  = ws + 19218432;                // f32 [NP][128]
  // hid bf16 [NP][512] = 12812288 float-units spans 9609216..22421504 (vbf+xr+qwe head, all dead by mlp1)
  short* wts   = (short*)(ws + 25624576);
  short* Wtq   = wts;                          // 6 x 16384 = 98304 shorts
  short* Wtk   = wts + 16384;
  short* Wtv   = wts + 32768;
  short* Wts_  = wts + 49152;
  short* Wtp   = wts + 65536;
  short* Wtqm  = wts + 81920;
  short* W1t   = wts + 98304;                  // [512][128] = 65536 shorts
  short* W2t   = wts + 163840;                 // [128][512] = 65536 shorts
  // weights total 229376 shorts = 114688 floats
  float* Wqm_f = ws + 25624576 + 114688;       // 16384 f32
  float* bqm   = Wqm_f + 16384;                // 128 f32
  int*   iw    = (int*)(bqm + 128);
  int* deg    = iw;
  int* off    = iw + 50000;
  int* cursor = iw + 100001;
  int* bucket = iw + 150001;

  float* res  = q;
  short* A2   = (short*)kbf;
  short* hid  = (short*)vbf;

  const int* srcIdx = edge_index;
  const int* dstIdx = edge_index + N_EDGES;

  // weight prep
  k_wqm<<<64, 256, 0, stream>>>(Wq, We, bq, Wqm_f, bqm);
  TC6 tc;
  tc.src[0]=Wq; tc.src[1]=Wk; tc.src[2]=Wv; tc.src[3]=Wss; tc.src[4]=Wp; tc.src[5]=Wqm_f;
  tc.dst[0]=Wtq; tc.dst[1]=Wtk; tc.dst[2]=Wtv; tc.dst[3]=Wts_; tc.dst[4]=Wtp; tc.dst[5]=Wtqm;
  k_tconv6<<<dim3(64,6), 256, 0, stream>>>(tc);
  k_tconv<<<256, 256, 0, stream>>>(W1, W1t, 128, 512);
  k_tconv<<<256, 256, 0, stream>>>(W2, W2t, 512, 128);

  // CSR
  hipMemsetAsync(deg, 0, N_NODES*sizeof(int), stream);
  k_deg<<<(N_EDGES+255)/256, 256, 0, stream>>>(dstIdx, deg);
  k_scan<<<1, 1024, 0, stream>>>(deg, off, cursor);
  k_scatter<<<(N_EDGES+255)/256, 256, 0, stream>>>(dstIdx, cursor, bucket);

  // main pipeline
  k_nodeproj<<<782, 256, 0, stream>>>(x, lnaw, lnab, Wtq, Wtqm, Wtk, Wtv, Wts_,
                                      bq, bqm, bk, bv, bss, q, qwe, kbf, vbf, xr);
  k_agg<<<N_NODES/4, 256, 0, stream>>>(q, qwe, kbf, vbf, edge_attr, We, be,
                                       srcIdx, off, bucket, xr);
  k_post<<<782, 256, 0, stream>>>(xr, x, Wtp, bp, lnmw, lnmb, res, A2);
  k_mlp1<<<dim3(782,2), 256, 0, stream>>>(A2, W1t, b1, hid);
  k_mlp2<<<782, 256, 0, stream>>>(hid, W2t, b2, res, (float*)d_out);

  hipMemcpyAsync((float*)d_out + (size_t)N_NODES*128, edge_attr,
                 (size_t)N_EDGES*16*sizeof(float), hipMemcpyDeviceToDevice, stream);
}

// Round 6
// 410.524 us; speedup vs baseline: 3.1129x; 1.0219x over previous
//
#include <hip/hip_runtime.h>
#include <math.h>

#define N_NODES 50000
#define N_EDGES 800000

typedef __attribute__((ext_vector_type(8))) short bf16x8;
typedef __attribute__((ext_vector_type(4))) float f32x4;

__device__ __forceinline__ short f2bf(float f){
  unsigned u = __float_as_uint(f);
  unsigned r = (u + 0x7FFFu + ((u >> 16) & 1u)) >> 16;
  return (short)r;
}

__device__ __forceinline__ float gelu_f(float x){
  float z = 0.7978845608028654f*(x + 0.044715f*x*x*x);
  float e = __expf(2.0f*z);
  return 0.5f*x*(2.0f - 2.0f/(e + 1.0f));   // 0.5x(1+tanh z), inf-safe
}

// ---------------- weight transpose + bf16 convert: Wt[n][k] = bf16(W[k][n]) ----------------
__global__ __launch_bounds__(256) void k_tconv(const float* __restrict__ W, short* __restrict__ Wt,
                                               int K, int Nn){
  int i = blockIdx.x*256 + threadIdx.x;
  if (i < K*Nn){
    int n = i / K, k = i - n*K;
    Wt[(size_t)n*K + k] = f2bf(W[(size_t)k*Nn + n]);
  }
}

struct TC6 { const float* src[6]; short* dst[6]; };
__global__ __launch_bounds__(256) void k_tconv6(TC6 t){
  int b = blockIdx.y;
  const float* W = t.src[b];
  short* Wt = t.dst[b];
  int i = blockIdx.x*256 + threadIdx.x;   // 64 blocks x 256 = 16384
  int n = i >> 7, k = i & 127;
  Wt[n*128 + k] = f2bf(W[k*128 + n]);
}

// ---------------- Wqm = Wq @ M, bqm = bq @ M  (M[d][h*16+c] = We[c,d] for d in head h) ----------------
__global__ __launch_bounds__(256) void k_wqm(const float* __restrict__ Wq, const float* __restrict__ We,
                                             const float* __restrict__ bq,
                                             float* __restrict__ Wqm, float* __restrict__ bqm){
  int i = blockIdx.x*256 + threadIdx.x;
  if (i < 16384){
    int k = i >> 7, j = i & 127;
    int h = j >> 4, c = j & 15;
    float s = 0.f;
    #pragma unroll
    for (int dd = 0; dd < 16; ++dd)
      s += Wq[k*128 + h*16 + dd] * We[c*128 + h*16 + dd];
    Wqm[i] = s;
    if (k == 0){
      float t = 0.f;
      #pragma unroll
      for (int dd = 0; dd < 16; ++dd)
        t += bq[h*16 + dd] * We[c*128 + h*16 + dd];
      bqm[j] = t;
    }
  }
}

// ---------------- CSR build ----------------
__global__ __launch_bounds__(256) void k_deg(const int* __restrict__ dst, int* __restrict__ deg){
  int i = blockIdx.x*256 + threadIdx.x;
  if (i < N_EDGES) atomicAdd(&deg[dst[i]], 1);
}

__global__ __launch_bounds__(1024) void k_scan(const int* __restrict__ deg,
                                               int* __restrict__ off, int* __restrict__ cursor){
  __shared__ int wsum[16];
  __shared__ int chunk_total;
  __shared__ int carry;
  int tid = threadIdx.x, lane = tid & 63, wid = tid >> 6;
  if (tid == 0) carry = 0;
  __syncthreads();
  for (int base = 0; base < N_NODES; base += 1024){
    int i = base + tid;
    int val = (i < N_NODES) ? deg[i] : 0;
    int incl = val;
    #pragma unroll
    for (int s = 1; s < 64; s <<= 1){
      int t = __shfl_up(incl, s, 64);
      if (lane >= s) incl += t;
    }
    if (lane == 63) wsum[wid] = incl;
    __syncthreads();
    if (tid < 16){
      int t = wsum[tid];
      int inc = t;
      #pragma unroll
      for (int s = 1; s < 16; s <<= 1){
        int u = __shfl_up(inc, s, 64);
        if (tid >= s) inc += u;
      }
      wsum[tid] = inc - t;
      if (tid == 15) chunk_total = inc;
    }
    __syncthreads();
    int excl = carry + wsum[wid] + (incl - val);
    if (i < N_NODES){ off[i] = excl; cursor[i] = excl; }
    __syncthreads();
    if (tid == 0) carry += chunk_total;
    __syncthreads();
  }
  if (threadIdx.x == 0) off[N_NODES] = carry;
}

// writes (src, eid) pairs bucketed by dst
__global__ __launch_bounds__(256) void k_scatter(const int* __restrict__ dst, const int* __restrict__ src,
                                                 int* __restrict__ cursor, int2* __restrict__ ebuf){
  int i = blockIdx.x*256 + threadIdx.x;
  if (i < N_EDGES){
    int d = dst[i];
    int pos = atomicAdd(&cursor[d], 1);
    ebuf[pos] = make_int2(src[i], i);
  }
}

// ---------------- node projections: LN(x) -> q, qWe, k(bf16), v(bf16), x_r ----------------
__global__ __launch_bounds__(256) void k_nodeproj(
  const float* __restrict__ x, const float* __restrict__ lnw, const float* __restrict__ lnb,
  const short* __restrict__ Wtq, const short* __restrict__ Wtqm,
  const short* __restrict__ Wtk, const short* __restrict__ Wtv, const short* __restrict__ Wts,
  const float* __restrict__ bq, const float* __restrict__ bqm,
  const float* __restrict__ bk, const float* __restrict__ bv, const float* __restrict__ bs,
  float* __restrict__ q, float* __restrict__ qwe,
  ushort* __restrict__ kb, ushort* __restrict__ vb, float* __restrict__ xr)
{
  __shared__ short A[64][136];
  int tid = threadIdx.x;
  int rbase = blockIdx.x * 64;

  // LN phase: 4 threads per row, 32 cols each
  {
    int r = tid >> 2, j = tid & 3;
    int row = rbase + r;
    bool ok = row < N_NODES;
    const float* xp = x + (size_t)row*128 + j*32;
    float vals[32];
    #pragma unroll
    for (int i = 0; i < 8; ++i){
      float4 t = ok ? *(const float4*)(xp + i*4) : make_float4(0,0,0,0);
      vals[i*4+0]=t.x; vals[i*4+1]=t.y; vals[i*4+2]=t.z; vals[i*4+3]=t.w;
    }
    float s = 0.f, s2 = 0.f;
    #pragma unroll
    for (int i = 0; i < 32; ++i){ s += vals[i]; s2 += vals[i]*vals[i]; }
    s  += __shfl_xor(s, 1, 64);  s  += __shfl_xor(s, 2, 64);
    s2 += __shfl_xor(s2, 1, 64); s2 += __shfl_xor(s2, 2, 64);
    float mean = s * 0.0078125f;
    float var  = s2 * 0.0078125f - mean*mean;
    float rstd = rsqrtf(var + 1e-5f);
    #pragma unroll
    for (int i = 0; i < 32; ++i){
      int col = j*32 + i;
      float xn = (vals[i]-mean)*rstd*lnw[col] + lnb[col];
      A[r][col] = f2bf(xn);
    }
  }
  __syncthreads();

  int lane = tid & 63, wave = tid >> 6;
  int row16 = lane & 15, kg = lane >> 4;
  int cb = wave * 32;

  auto gemm = [&](const short* __restrict__ B, const float* __restrict__ bias,
                  float* __restrict__ Of, ushort* __restrict__ Ob){
    f32x4 acc[4][2] = {};
    #pragma unroll
    for (int kk = 0; kk < 128; kk += 32){
      int k0 = kk + kg*8;
      bf16x8 a0 = *(const bf16x8*)&A[ 0 + row16][k0];
      bf16x8 a1 = *(const bf16x8*)&A[16 + row16][k0];
      bf16x8 a2 = *(const bf16x8*)&A[32 + row16][k0];
      bf16x8 a3 = *(const bf16x8*)&A[48 + row16][k0];
      bf16x8 b0 = *(const bf16x8*)&B[(size_t)(cb +      row16)*128 + k0];
      bf16x8 b1 = *(const bf16x8*)&B[(size_t)(cb + 16 + row16)*128 + k0];
      acc[0][0] = __builtin_amdgcn_mfma_f32_16x16x32_bf16(a0, b0, acc[0][0], 0,0,0);
      acc[1][0] = __builtin_amdgcn_mfma_f32_16x16x32_bf16(a1, b0, acc[1][0], 0,0,0);
      acc[2][0] = __builtin_amdgcn_mfma_f32_16x16x32_bf16(a2, b0, acc[2][0], 0,0,0);
      acc[3][0] = __builtin_amdgcn_mfma_f32_16x16x32_bf16(a3, b0, acc[3][0], 0,0,0);
      acc[0][1] = __builtin_amdgcn_mfma_f32_16x16x32_bf16(a0, b1, acc[0][1], 0,0,0);
      acc[1][1] = __builtin_amdgcn_mfma_f32_16x16x32_bf16(a1, b1, acc[1][1], 0,0,0);
      acc[2][1] = __builtin_amdgcn_mfma_f32_16x16x32_bf16(a2, b1, acc[2][1], 0,0,0);
      acc[3][1] = __builtin_amdgcn_mfma_f32_16x16x32_bf16(a3, b1, acc[3][1], 0,0,0);
    }
    float bv0 = bias[cb + row16], bv1 = bias[cb + 16 + row16];
    #pragma unroll
    for (int rt = 0; rt < 4; ++rt){
      #pragma unroll
      for (int i = 0; i < 4; ++i){
        int row = rbase + rt*16 + kg*4 + i;
        if (row < N_NODES){
          float v0 = acc[rt][0][i] + bv0;
          float v1 = acc[rt][1][i] + bv1;
          if (Of){
            Of[(size_t)row*128 + cb      + row16] = v0;
            Of[(size_t)row*128 + cb + 16 + row16] = v1;
          } else {
            Ob[(size_t)row*128 + cb      + row16] = (ushort)f2bf(v0);
            Ob[(size_t)row*128 + cb + 16 + row16] = (ushort)f2bf(v1);
          }
        }
      }
    }
  };
  gemm(Wtq,  bq,  q,   nullptr);
  gemm(Wtqm, bqm, qwe, nullptr);
  gemm(Wtk,  bk,  nullptr, kb);
  gemm(Wtv,  bv,  nullptr, vb);
  gemm(Wts,  bs,  xr,  nullptr);
}

// ---------------- edge attention aggregation: 2 nodes per wave (32 lanes/node, 4 dims/lane) ----------------
// score = (q.k[src] + <ea, qWe_h>)/4   (q.be term dropped: softmax shift-invariant)
// out   = (sum pe*v + We^T (sum pe*ea))/den + be
__global__ __launch_bounds__(256) void k_agg(
  const float* __restrict__ q, const float* __restrict__ qwe,
  const ushort* __restrict__ kbf, const ushort* __restrict__ vbf,
  const float* __restrict__ edge_attr, const float* __restrict__ We, const float* __restrict__ be,
  const int2* __restrict__ ebuf, const int* __restrict__ off,
  float* __restrict__ xr)
{
  int tid = threadIdx.x;
  int node = blockIdx.x*8 + (tid >> 5);
  int l = tid & 31;          // lane within half-wave
  int d0 = l*4;              // dims d0..d0+3 (global 0..127)
  int h  = l >> 2;           // head
  int c0 = (l & 3)*4;        // edge-dim slice

  float4 qv = *(const float4*)&q[(size_t)node*128 + d0];
  float4 qe = *(const float4*)&qwe[(size_t)node*128 + h*16 + c0];
  int beg = off[node], end = off[node+1];
  float m = -INFINITY, den = 0.f;
  float4 va = make_float4(0,0,0,0);
  float4 S  = make_float4(0,0,0,0);

  int p = beg;
  for (; p + 4 <= end; p += 4){
    int2 pr0 = ebuf[p+0];
    int2 pr1 = ebuf[p+1];
    int2 pr2 = ebuf[p+2];
    int2 pr3 = ebuf[p+3];
    uint2 kw0 = *(const uint2*)&kbf[(size_t)pr0.x*128 + d0];
    uint2 kw1 = *(const uint2*)&kbf[(size_t)pr1.x*128 + d0];
    uint2 kw2 = *(const uint2*)&kbf[(size_t)pr2.x*128 + d0];
    uint2 kw3 = *(const uint2*)&kbf[(size_t)pr3.x*128 + d0];
    uint2 vw0 = *(const uint2*)&vbf[(size_t)pr0.x*128 + d0];
    uint2 vw1 = *(const uint2*)&vbf[(size_t)pr1.x*128 + d0];
    uint2 vw2 = *(const uint2*)&vbf[(size_t)pr2.x*128 + d0];
    uint2 vw3 = *(const uint2*)&vbf[(size_t)pr3.x*128 + d0];
    float4 e0 = *(const float4*)&edge_attr[(size_t)pr0.y*16 + c0];
    float4 e1 = *(const float4*)&edge_attr[(size_t)pr1.y*16 + c0];
    float4 e2 = *(const float4*)&edge_attr[(size_t)pr2.y*16 + c0];
    float4 e3 = *(const float4*)&edge_attr[(size_t)pr3.y*16 + c0];

    float p0 = qv.x*__uint_as_float(kw0.x<<16) + qv.y*__uint_as_float(kw0.x&0xffff0000u)
             + qv.z*__uint_as_float(kw0.y<<16) + qv.w*__uint_as_float(kw0.y&0xffff0000u)
             + qe.x*e0.x + qe.y*e0.y + qe.z*e0.z + qe.w*e0.w;
    float p1 = qv.x*__uint_as_float(kw1.x<<16) + qv.y*__uint_as_float(kw1.x&0xffff0000u)
             + qv.z*__uint_as_float(kw1.y<<16) + qv.w*__uint_as_float(kw1.y&0xffff0000u)
             + qe.x*e1.x + qe.y*e1.y + qe.z*e1.z + qe.w*e1.w;
    float p2 = qv.x*__uint_as_float(kw2.x<<16) + qv.y*__uint_as_float(kw2.x&0xffff0000u)
             + qv.z*__uint_as_float(kw2.y<<16) + qv.w*__uint_as_float(kw2.y&0xffff0000u)
             + qe.x*e2.x + qe.y*e2.y + qe.z*e2.z + qe.w*e2.w;
    float p3 = qv.x*__uint_as_float(kw3.x<<16) + qv.y*__uint_as_float(kw3.x&0xffff0000u)
             + qv.z*__uint_as_float(kw3.y<<16) + qv.w*__uint_as_float(kw3.y&0xffff0000u)
             + qe.x*e3.x + qe.y*e3.y + qe.z*e3.z + qe.w*e3.w;
    p0 += __shfl_xor(p0,1,64); p0 += __shfl_xor(p0,2,64);
    p1 += __shfl_xor(p1,1,64); p1 += __shfl_xor(p1,2,64);
    p2 += __shfl_xor(p2,1,64); p2 += __shfl_xor(p2,2,64);
    p3 += __shfl_xor(p3,1,64); p3 += __shfl_xor(p3,2,64);
    float sc0 = p0*0.25f, sc1 = p1*0.25f, sc2 = p2*0.25f, sc3 = p3*0.25f;
    float mn = fmaxf(fmaxf(m, fmaxf(sc0,sc1)), fmaxf(sc2,sc3));
    float corr = __expf(m - mn);
    float w0 = __expf(sc0 - mn), w1 = __expf(sc1 - mn);
    float w2 = __expf(sc2 - mn), w3 = __expf(sc3 - mn);
    den = den*corr + ((w0+w1)+(w2+w3));
    va.x = va.x*corr + (w0*__uint_as_float(vw0.x<<16)        + w1*__uint_as_float(vw1.x<<16))
                     + (w2*__uint_as_float(vw2.x<<16)        + w3*__uint_as_float(vw3.x<<16));
    va.y = va.y*corr + (w0*__uint_as_float(vw0.x&0xffff0000u)+ w1*__uint_as_float(vw1.x&0xffff0000u))
                     + (w2*__uint_as_float(vw2.x&0xffff0000u)+ w3*__uint_as_float(vw3.x&0xffff0000u));
    va.z = va.z*corr + (w0*__uint_as_float(vw0.y<<16)        + w1*__uint_as_float(vw1.y<<16))
                     + (w2*__uint_as_float(vw2.y<<16)        + w3*__uint_as_float(vw3.y<<16));
    va.w = va.w*corr + (w0*__uint_as_float(vw0.y&0xffff0000u)+ w1*__uint_as_float(vw1.y&0xffff0000u))
                     + (w2*__uint_as_float(vw2.y&0xffff0000u)+ w3*__uint_as_float(vw3.y&0xffff0000u));
    S.x = S.x*corr + (w0*e0.x + w1*e1.x) + (w2*e2.x + w3*e3.x);
    S.y = S.y*corr + (w0*e0.y + w1*e1.y) + (w2*e2.y + w3*e3.y);
    S.z = S.z*corr + (w0*e0.z + w1*e1.z) + (w2*e2.z + w3*e3.z);
    S.w = S.w*corr + (w0*e0.w + w1*e1.w) + (w2*e2.w + w3*e3.w);
    m = mn;
  }
  for (; p < end; ++p){
    int2 pr = ebuf[p];
    uint2 kw = *(const uint2*)&kbf[(size_t)pr.x*128 + d0];
    uint2 vw = *(const uint2*)&vbf[(size_t)pr.x*128 + d0];
    float4 ev = *(const float4*)&edge_attr[(size_t)pr.y*16 + c0];
    float pp = qv.x*__uint_as_float(kw.x<<16) + qv.y*__uint_as_float(kw.x&0xffff0000u)
             + qv.z*__uint_as_float(kw.y<<16) + qv.w*__uint_as_float(kw.y&0xffff0000u)
             + qe.x*ev.x + qe.y*ev.y + qe.z*ev.z + qe.w*ev.w;
    pp += __shfl_xor(pp,1,64); pp += __shfl_xor(pp,2,64);
    float sc = pp*0.25f;
    float mn = fmaxf(m, sc);
    float corr = __expf(m - mn);
    float pe = __expf(sc - mn);
    den = den*corr + pe;
    va.x = va.x*corr + pe*__uint_as_float(vw.x<<16);
    va.y = va.y*corr + pe*__uint_as_float(vw.x&0xffff0000u);
    va.z = va.z*corr + pe*__uint_as_float(vw.y<<16);
    va.w = va.w*corr + pe*__uint_as_float(vw.y&0xffff0000u);
    S.x = S.x*corr + pe*ev.x;
    S.y = S.y*corr + pe*ev.y;
    S.z = S.z*corr + pe*ev.z;
    S.w = S.w*corr + pe*ev.w;
    m = mn;
  }

  if (end > beg){
    float inv = 1.0f/den;
    float4 acc = va;
    int gb = (tid & 63) & 60;   // 4-lane group base (wave-wide lane index)
    #pragma unroll
    for (int g = 0; g < 4; ++g){
      float s0 = __shfl(S.x, gb+g, 64);
      float s1 = __shfl(S.y, gb+g, 64);
      float s2 = __shfl(S.z, gb+g, 64);
      float s3 = __shfl(S.w, gb+g, 64);
      float4 w0 = *(const float4*)&We[(g*4+0)*128 + d0];
      float4 w1 = *(const float4*)&We[(g*4+1)*128 + d0];
      float4 w2 = *(const float4*)&We[(g*4+2)*128 + d0];
      float4 w3 = *(const float4*)&We[(g*4+3)*128 + d0];
      acc.x += s0*w0.x + s1*w1.x + s2*w2.x + s3*w3.x;
      acc.y += s0*w0.y + s1*w1.y + s2*w2.y + s3*w3.y;
      acc.z += s0*w0.z + s1*w1.z + s2*w2.z + s3*w3.z;
      acc.w += s0*w0.w + s1*w1.w + s2*w2.w + s3*w3.w;
    }
    float4 bev = *(const float4*)&be[d0];
    float4 xv = *(const float4*)&xr[(size_t)node*128 + d0];
    xv.x += acc.x*inv + bev.x;
    xv.y += acc.y*inv + bev.y;
    xv.z += acc.z*inv + bev.z;
    xv.w += acc.w*inv + bev.w;
    *(float4*)&xr[(size_t)node*128 + d0] = xv;
  }
}

// ---------------- post: res = aggout@Wp + bp + x ; A2 = bf16(LN(res)) ----------------
__global__ __launch_bounds__(256) void k_post(
  const float* __restrict__ aggout, const float* __restrict__ x,
  const short* __restrict__ Wtp, const float* __restrict__ bp,
  const float* __restrict__ lnw, const float* __restrict__ lnb,
  float* __restrict__ res, short* __restrict__ A2)
{
  __shared__ short A[64][136];
  __shared__ float rf[64][132];
  int tid = threadIdx.x;
  int rbase = blockIdx.x * 64;

  {
    int r = tid >> 2, j = tid & 3;
    int row = rbase + r;
    const float* p = aggout + (size_t)row*128 + j*32;
    #pragma unroll
    for (int i = 0; i < 8; ++i){
      float4 t = *(const float4*)(p + i*4);
      int c = j*32 + i*4;
      A[r][c+0] = f2bf(t.x); A[r][c+1] = f2bf(t.y);
      A[r][c+2] = f2bf(t.z); A[r][c+3] = f2bf(t.w);
    }
  }
  __syncthreads();

  int lane = tid & 63, wave = tid >> 6;
  int row16 = lane & 15, kg = lane >> 4;
  int cb = wave * 32;

  f32x4 acc[4][2] = {};
  #pragma unroll
  for (int kk = 0; kk < 128; kk += 32){
    int k0 = kk + kg*8;
    bf16x8 a0 = *(const bf16x8*)&A[ 0 + row16][k0];
    bf16x8 a1 = *(const bf16x8*)&A[16 + row16][k0];
    bf16x8 a2 = *(const bf16x8*)&A[32 + row16][k0];
    bf16x8 a3 = *(const bf16x8*)&A[48 + row16][k0];
    bf16x8 b0 = *(const bf16x8*)&Wtp[(size_t)(cb +      row16)*128 + k0];
    bf16x8 b1 = *(const bf16x8*)&Wtp[(size_t)(cb + 16 + row16)*128 + k0];
    acc[0][0] = __builtin_amdgcn_mfma_f32_16x16x32_bf16(a0, b0, acc[0][0], 0,0,0);
    acc[1][0] = __builtin_amdgcn_mfma_f32_16x16x32_bf16(a1, b0, acc[1][0], 0,0,0);
    acc[2][0] = __builtin_amdgcn_mfma_f32_16x16x32_bf16(a2, b0, acc[2][0], 0,0,0);
    acc[3][0] = __builtin_amdgcn_mfma_f32_16x16x32_bf16(a3, b0, acc[3][0], 0,0,0);
    acc[0][1] = __builtin_amdgcn_mfma_f32_16x16x32_bf16(a0, b1, acc[0][1], 0,0,0);
    acc[1][1] = __builtin_amdgcn_mfma_f32_16x16x32_bf16(a1, b1, acc[1][1], 0,0,0);
    acc[2][1] = __builtin_amdgcn_mfma_f32_16x16x32_bf16(a2, b1, acc[2][1], 0,0,0);
    acc[3][1] = __builtin_amdgcn_mfma_f32_16x16x32_bf16(a3, b1, acc[3][1], 0,0,0);
  }
  float bv0 = bp[cb + row16], bv1 = bp[cb + 16 + row16];
  #pragma unroll
  for (int rt = 0; rt < 4; ++rt){
    #pragma unroll
    for (int i = 0; i < 4; ++i){
      int rl = rt*16 + kg*4 + i;
      int row = rbase + rl;
      float v0 = acc[rt][0][i] + bv0;
      float v1 = acc[rt][1][i] + bv1;
      if (row < N_NODES){
        v0 += x[(size_t)row*128 + cb      + row16];
        v1 += x[(size_t)row*128 + cb + 16 + row16];
        res[(size_t)row*128 + cb      + row16] = v0;
        res[(size_t)row*128 + cb + 16 + row16] = v1;
      }
      rf[rl][cb      + row16] = v0;
      rf[rl][cb + 16 + row16] = v1;
    }
  }
  __syncthreads();

  {
    int r = tid >> 2, j = tid & 3;
    int row = rbase + r;
    float vals[32];
    #pragma unroll
    for (int i = 0; i < 8; ++i){
      float4 t = *(const float4*)&rf[r][j*32 + i*4];
      vals[i*4+0]=t.x; vals[i*4+1]=t.y; vals[i*4+2]=t.z; vals[i*4+3]=t.w;
    }
    float s = 0.f, s2 = 0.f;
    #pragma unroll
    for (int i = 0; i < 32; ++i){ s += vals[i]; s2 += vals[i]*vals[i]; }
    s  += __shfl_xor(s, 1, 64);  s  += __shfl_xor(s, 2, 64);
    s2 += __shfl_xor(s2, 1, 64); s2 += __shfl_xor(s2, 2, 64);
    float mean = s * 0.0078125f;
    float var  = s2 * 0.0078125f - mean*mean;
    float rstd = rsqrtf(var + 1e-5f);
    #pragma unroll
    for (int i = 0; i < 32; ++i){
      int col = j*32 + i;
      float xn = (vals[i]-mean)*rstd*lnw[col] + lnb[col];
      A2[(size_t)row*128 + col] = f2bf(xn);
    }
  }
}

// ---------------- mlp1: hid = bf16(gelu(A2 @ W1 + b1)) ----------------
__global__ __launch_bounds__(256) void k_mlp1(
  const short* __restrict__ A2, const short* __restrict__ W1t, const float* __restrict__ b1,
  short* __restrict__ hid)
{
  __shared__ short A[64][136];
  int tid = threadIdx.x;
  int rbase = blockIdx.x * 64;
  int ch = blockIdx.y;
  for (int idx = tid; idx < 1024; idx += 256){
    int r = idx >> 4, g = idx & 15;
    *(uint4*)&A[r][g*8] = *(const uint4*)&A2[((size_t)(rbase + r))*128 + g*8];
  }
  __syncthreads();

  int lane = tid & 63, wave = tid >> 6;
  int row16 = lane & 15, kg = lane >> 4;
  int cb = ch*256 + wave*64;

  f32x4 acc[4][4] = {};
  #pragma unroll
  for (int kk = 0; kk < 128; kk += 32){
    int k0 = kk + kg*8;
    bf16x8 a[4], b[4];
    #pragma unroll
    for (int rt = 0; rt < 4; ++rt) a[rt] = *(const bf16x8*)&A[rt*16 + row16][k0];
    #pragma unroll
    for (int ct = 0; ct < 4; ++ct) b[ct] = *(const bf16x8*)&W1t[(size_t)(cb + ct*16 + row16)*128 + k0];
    #pragma unroll
    for (int rt = 0; rt < 4; ++rt)
      #pragma unroll
      for (int ct = 0; ct < 4; ++ct)
        acc[rt][ct] = __builtin_amdgcn_mfma_f32_16x16x32_bf16(a[rt], b[ct], acc[rt][ct], 0,0,0);
  }
  float bv[4];
  #pragma unroll
  for (int ct = 0; ct < 4; ++ct) bv[ct] = b1[cb + ct*16 + row16];
  #pragma unroll
  for (int rt = 0; rt < 4; ++rt){
    #pragma unroll
    for (int ct = 0; ct < 4; ++ct){
      #pragma unroll
      for (int i = 0; i < 4; ++i){
        int row = rbase + rt*16 + kg*4 + i;
        hid[(size_t)row*512 + cb + ct*16 + row16] = f2bf(gelu_f(acc[rt][ct][i] + bv[ct]));
      }
    }
  }
}

// ---------------- mlp2: out = hid @ W2 + b2 + res ----------------
__global__ __launch_bounds__(256) void k_mlp2(
  const short* __restrict__ hid, const short* __restrict__ W2t, const float* __restrict__ b2,
  const float* __restrict__ res, float* __restrict__ out)
{
  __shared__ short A[64][136];
  int tid = threadIdx.x;
  int rbase = blockIdx.x * 64;
  int lane = tid & 63, wave = tid >> 6;
  int row16 = lane & 15, kg = lane >> 4;
  int cb = wave * 32;

  f32x4 acc[4][2] = {};
  for (int kc = 0; kc < 4; ++kc){
    __syncthreads();
    for (int idx = tid; idx < 1024; idx += 256){
      int r = idx >> 4, g = idx & 15;
      *(uint4*)&A[r][g*8] = *(const uint4*)&hid[((size_t)(rbase + r))*512 + kc*128 + g*8];
    }
    __syncthreads();
    #pragma unroll
    for (int kk = 0; kk < 128; kk += 32){
      int k0 = kk + kg*8;
      bf16x8 a0 = *(const bf16x8*)&A[ 0 + row16][k0];
      bf16x8 a1 = *(const bf16x8*)&A[16 + row16][k0];
      bf16x8 a2 = *(const bf16x8*)&A[32 + row16][k0];
      bf16x8 a3 = *(const bf16x8*)&A[48 + row16][k0];
      bf16x8 b0 = *(const bf16x8*)&W2t[(size_t)(cb +      row16)*512 + kc*128 + k0];
      bf16x8 b1 = *(const bf16x8*)&W2t[(size_t)(cb + 16 + row16)*512 + kc*128 + k0];
      acc[0][0] = __builtin_amdgcn_mfma_f32_16x16x32_bf16(a0, b0, acc[0][0], 0,0,0);
      acc[1][0] = __builtin_amdgcn_mfma_f32_16x16x32_bf16(a1, b0, acc[1][0], 0,0,0);
      acc[2][0] = __builtin_amdgcn_mfma_f32_16x16x32_bf16(a2, b0, acc[2][0], 0,0,0);
      acc[3][0] = __builtin_amdgcn_mfma_f32_16x16x32_bf16(a3, b0, acc[3][0], 0,0,0);
      acc[0][1] = __builtin_amdgcn_mfma_f32_16x16x32_bf16(a0, b1, acc[0][1], 0,0,0);
      acc[1][1] = __builtin_amdgcn_mfma_f32_16x16x32_bf16(a1, b1, acc[1][1], 0,0,0);
      acc[2][1] = __builtin_amdgcn_mfma_f32_16x16x32_bf16(a2, b1, acc[2][1], 0,0,0);
      acc[3][1] = __builtin_amdgcn_mfma_f32_16x16x32_bf16(a3, b1, acc[3][1], 0,0,0);
    }
  }
  float bv0 = b2[cb + row16], bv1 = b2[cb + 16 + row16];
  #pragma unroll
  for (int rt = 0; rt < 4; ++rt){
    #pragma unroll
    for (int i = 0; i < 4; ++i){
      int row = rbase + rt*16 + kg*4 + i;
      if (row < N_NODES){
        out[(size_t)row*128 + cb      + row16] = acc[rt][0][i] + bv0 + res[(size_t)row*128 + cb      + row16];
        out[(size_t)row*128 + cb + 16 + row16] = acc[rt][1][i] + bv1 + res[(size_t)row*128 + cb + 16 + row16];
      }
    }
  }
}

extern "C" void kernel_launch(void* const* d_in, const int* in_sizes, int n_in,
                              void* d_out, int out_size, void* d_ws, size_t ws_size,
                              hipStream_t stream)
{
  const float* x        = (const float*)d_in[0];
  const float* edge_attr= (const float*)d_in[1];
  const int*   edge_index=(const int*)d_in[2];
  const float* Wq = (const float*)d_in[3];  const float* bq = (const float*)d_in[4];
  const float* Wk = (const float*)d_in[5];  const float* bk = (const float*)d_in[6];
  const float* Wv = (const float*)d_in[7];  const float* bv = (const float*)d_in[8];
  const float* Wss= (const float*)d_in[9];  const float* bss= (const float*)d_in[10];
  const float* We = (const float*)d_in[11]; const float* be = (const float*)d_in[12];
  const float* Wp = (const float*)d_in[13]; const float* bp = (const float*)d_in[14];
  const float* lnaw=(const float*)d_in[15]; const float* lnab=(const float*)d_in[16];
  const float* lnmw=(const float*)d_in[17]; const float* lnmb=(const float*)d_in[18];
  const float* W1 = (const float*)d_in[19]; const float* b1 = (const float*)d_in[20];
  const float* W2 = (const float*)d_in[21]; const float* b2 = (const float*)d_in[22];

  float* ws = (float*)d_ws;
  // N_PAD = 50048 rows
  const size_t NP128 = 6406144;  // f32 [NP][128]
  const size_t NPH   = 3203072;  // bf16 [NP][128] in float-units
  float*  q    = ws;                           // f32; reused as res
  ushort* kbf  = (ushort*)(ws + NP128);        // bf16 [NP][128]; reused as A2
  ushort* vbf  = (ushort*)(ws + NP128 + NPH);  // bf16 [NP][128]; start of hid region
  float*  xr   = ws + 12812288;                // f32 [NP][128]
  float*  qwe  = ws + 19218432;                // f32 [NP][128]
  // hid bf16 [NP][512] = 12812288 float-units spans 9609216..22421504 (vbf+xr+qwe head, all dead by mlp1)
  short* wts   = (short*)(ws + 25624576);
  short* Wtq   = wts;                          // 6 x 16384 = 98304 shorts
  short* Wtk   = wts + 16384;
  short* Wtv   = wts + 32768;
  short* Wts_  = wts + 49152;
  short* Wtp   = wts + 65536;
  short* Wtqm  = wts + 81920;
  short* W1t   = wts + 98304;                  // [512][128] = 65536 shorts
  short* W2t   = wts + 163840;                 // [128][512] = 65536 shorts
  // weights total 229376 shorts = 114688 floats
  float* Wqm_f = ws + 25624576 + 114688;       // 16384 f32
  float* bqm   = Wqm_f + 16384;                // 128 f32
  int*   iw    = (int*)(bqm + 128);
  int* deg    = iw;                            // N
  int* off    = iw + 50000;                    // N+1
  int* cursor = iw + 100001;                   // N
  int2* ebuf  = (int2*)(iw + 150002);          // E pairs (8B-aligned: base offset even)

  float* res  = q;
  short* A2   = (short*)kbf;
  short* hid  = (short*)vbf;

  const int* srcIdx = edge_index;
  const int* dstIdx = edge_index + N_EDGES;

  // weight prep
  k_wqm<<<64, 256, 0, stream>>>(Wq, We, bq, Wqm_f, bqm);
  TC6 tc;
  tc.src[0]=Wq; tc.src[1]=Wk; tc.src[2]=Wv; tc.src[3]=Wss; tc.src[4]=Wp; tc.src[5]=Wqm_f;
  tc.dst[0]=Wtq; tc.dst[1]=Wtk; tc.dst[2]=Wtv; tc.dst[3]=Wts_; tc.dst[4]=Wtp; tc.dst[5]=Wtqm;
  k_tconv6<<<dim3(64,6), 256, 0, stream>>>(tc);
  k_tconv<<<256, 256, 0, stream>>>(W1, W1t, 128, 512);
  k_tconv<<<256, 256, 0, stream>>>(W2, W2t, 512, 128);

  // CSR
  hipMemsetAsync(deg, 0, N_NODES*sizeof(int), stream);
  k_deg<<<(N_EDGES+255)/256, 256, 0, stream>>>(dstIdx, deg);
  k_scan<<<1, 1024, 0, stream>>>(deg, off, cursor);
  k_scatter<<<(N_EDGES+255)/256, 256, 0, stream>>>(dstIdx, srcIdx, cursor, ebuf);

  // main pipeline
  k_nodeproj<<<782, 256, 0, stream>>>(x, lnaw, lnab, Wtq, Wtqm, Wtk, Wtv, Wts_,
                                      bq, bqm, bk, bv, bss, q, qwe, kbf, vbf, xr);
  k_agg<<<N_NODES/8, 256, 0, stream>>>(q, qwe, kbf, vbf, edge_attr, We, be,
                                       ebuf, off, xr);
  k_post<<<782, 256, 0, stream>>>(xr, x, Wtp, bp, lnmw, lnmb, res, A2);
  k_mlp1<<<dim3(782,2), 256, 0, stream>>>(A2, W1t, b1, hid);
  k_mlp2<<<782, 256, 0, stream>>>(hid, W2t, b2, res, (float*)d_out);

  hipMemcpyAsync((float*)d_out + (size_t)N_NODES*128, edge_attr,
                 (size_t)N_EDGES*16*sizeof(float), hipMemcpyDeviceToDevice, stream);
}